// Round 8
// baseline (5157.220 us; speedup 1.0000x reference)
//
#include <hip/hip_runtime.h>

#define NN_ 131072      // T*N
#define T_ 64
#define N_ 2048
#define E_ 2097152
#define FIN_ 16

typedef unsigned short ushort_t;
typedef unsigned int uint_t;

// memory-clobber LDS barrier (fallback kernel only)
#define LBAR() asm volatile("s_waitcnt lgkmcnt(0)\n\ts_barrier" ::: "memory")

__device__ __forceinline__ float bf2f(ushort_t u) {
  return __uint_as_float(((uint_t)u) << 16);
}
__device__ __forceinline__ ushort_t f2bf(float f) {
  uint_t b = __float_as_uint(f);
  b += 0x7fffu + ((b >> 16) & 1u);   // round-to-nearest-even
  return (ushort_t)(b >> 16);
}

// ---------------- zero cnt + accum ----------------
__global__ void k_zero(uint_t* __restrict__ cnt, float* __restrict__ accum) {
  int i = blockIdx.x * 256 + threadIdx.x;
  if (i < NN_) cnt[i] = 0u;
  if (i < 2) accum[i] = 0.f;
}

// ---------------- histogram of col ----------------
__global__ void k_hist(const int* __restrict__ col, uint_t* __restrict__ cnt) {
  int e = blockIdx.x * 256 + threadIdx.x;
  atomicAdd(&cnt[col[e]], 1u);
}

// ---------------- dinv from counts (+1 self loop) ----------------
__global__ void k_dinvc(const uint_t* __restrict__ cnt, float* __restrict__ dinv) {
  int v = blockIdx.x * 256 + threadIdx.x;
  dinv[v] = rsqrtf((float)cnt[v] + 1.f);
}

// ---------------- per-256-chunk sums ----------------
__global__ void k_bsum(const uint_t* __restrict__ cnt, uint_t* __restrict__ bsum) {
  int t = threadIdx.x;
  uint_t v = cnt[blockIdx.x * 256 + t];
  for (int off = 32; off; off >>= 1) v += __shfl_down(v, off);
  __shared__ uint_t s4[4];
  if ((t & 63) == 0) s4[t >> 6] = v;
  __syncthreads();
  if (t == 0) bsum[blockIdx.x] = s4[0] + s4[1] + s4[2] + s4[3];
}

// ---------------- exclusive scan of 512 chunk sums (1 block) ----------------
__global__ void k_scan512(uint_t* __restrict__ bsum) {
  __shared__ uint_t sd[512];
  int t = threadIdx.x;
  uint_t v = bsum[t];
  sd[t] = v;
  __syncthreads();
  for (int off = 1; off < 512; off <<= 1) {
    uint_t x = (t >= off) ? sd[t - off] : 0u;
    __syncthreads();
    sd[t] += x;
    __syncthreads();
  }
  bsum[t] = sd[t] - v;   // exclusive
}

// ---------------- per-chunk exclusive scan + chunk offset ----------------
__global__ void k_scanadd(const uint_t* __restrict__ cnt, const uint_t* __restrict__ bsum,
                          uint_t* __restrict__ start, uint_t* __restrict__ cursor) {
  int t = threadIdx.x;
  int i = blockIdx.x * 256 + t;
  uint_t v = cnt[i];
  __shared__ uint_t sd[256];
  sd[t] = v;
  __syncthreads();
  for (int off = 1; off < 256; off <<= 1) {
    uint_t x = (t >= off) ? sd[t - off] : 0u;
    __syncthreads();
    sd[t] += x;
    __syncthreads();
  }
  uint_t excl = sd[t] - v + bsum[blockIdx.x];
  start[i] = excl;
  cursor[i] = excl;
  if (i == NN_ - 1) start[NN_] = E_;
}

// ---------------- counting-sort placement: srow grouped by col ----------------
__global__ void k_place(const int* __restrict__ row, const int* __restrict__ col,
                        uint_t* __restrict__ cursor, int* __restrict__ srow) {
  int e = blockIdx.x * 256 + threadIdx.x;
  int c = col[e];
  uint_t pos = atomicAdd(&cursor[c], 1u);
  srow[pos] = row[e];
}

// ---------------- GEMM (NN x K) @ (K x 64), writes dinv-prescaled rows -------
template <int K, bool RELU_IN>
__global__ void k_gemm(const float* __restrict__ X, const float* __restrict__ W,
                       const float* __restrict__ bin, const float* __restrict__ dinv,
                       float* __restrict__ xws) {
  __shared__ float xs[4 * K];
  const int tid = threadIdx.x;
  const int v0 = blockIdx.x * 4;
  for (int t = tid; t < 4 * K; t += 256) {
    float v = X[(size_t)v0 * K + t];
    if (RELU_IN) v = fmaxf(v + bin[t & (K - 1)], 0.f);
    xs[t] = v;
  }
  __syncthreads();
  const int v = v0 + (tid >> 6);
  const int j = tid & 63;
  const float* xr = &xs[(tid >> 6) * K];
  float acc = 0.f;
#pragma unroll
  for (int k = 0; k < K; ++k) acc = fmaf(xr[k], W[k * 64 + j], acc);
  xws[(size_t)v * 64 + j] = dinv[v] * acc;
}

// ---------------- column-gather aggregation (no atomics) ----------------------
__global__ void k_colagg(const int* __restrict__ srow, const uint_t* __restrict__ start,
                         const float* __restrict__ dinv, const float* __restrict__ xws,
                         float* __restrict__ agg) {
  int c = blockIdx.x * 4 + (threadIdx.x >> 6);
  int lane = threadIdx.x & 63;
  uint_t s = start[c], e = start[c + 1];
  float acc = xws[(size_t)c * 64 + lane];      // self loop
  for (uint_t i = s; i < e; ++i) {
    int r = srow[i];
    acc += xws[(size_t)r * 64 + lane];
  }
  agg[(size_t)c * 64 + lane] = dinv[c] * acc;
}

// ---------------- gate-preactivation GEMM (bf16 out) --------------------------
__global__ __launch_bounds__(256) void k_gates(
    const float* __restrict__ A, const float* __restrict__ b2,
    const float* __restrict__ WihF, const float* __restrict__ bihF,
    const float* __restrict__ bhhF,
    const float* __restrict__ WihB, const float* __restrict__ bihB,
    const float* __restrict__ bhhB,
    ushort_t* __restrict__ gx) {
  const int dir = blockIdx.x >> 11;
  const int v0 = (blockIdx.x & 2047) * 64;
  const float* Wih = dir ? WihB : WihF;
  const float* bih = dir ? bihB : bihF;
  const float* bhh = dir ? bhhB : bhhF;
  const int t = threadIdx.x;

  float w[64];
#pragma unroll
  for (int k = 0; k < 64; k += 4)
    *reinterpret_cast<float4*>(&w[k]) = *reinterpret_cast<const float4*>(&Wih[t * 64 + k]);
  const float bias = bih[t] + bhh[t];

  __shared__ float xs[64 * 64];
#pragma unroll
  for (int u = 0; u < 16; ++u) {
    int idx = u * 256 + t;
    xs[idx] = fmaxf(A[(size_t)v0 * 64 + idx] + b2[idx & 63], 0.f);
  }
  __syncthreads();

  ushort_t* gp = gx + ((size_t)(dir ? NN_ : 0) + v0) * 256 + t;
  for (int r = 0; r < 64; ++r) {
    const float* xr = &xs[r * 64];
    float a0 = 0.f, a1 = 0.f, a2 = 0.f, a3 = 0.f;
#pragma unroll
    for (int k = 0; k < 64; k += 16) {
      float4 x0 = *reinterpret_cast<const float4*>(&xr[k]);
      float4 x1 = *reinterpret_cast<const float4*>(&xr[k + 4]);
      float4 x2 = *reinterpret_cast<const float4*>(&xr[k + 8]);
      float4 x3 = *reinterpret_cast<const float4*>(&xr[k + 12]);
      a0 = fmaf(x0.x, w[k+0], a0);  a0 = fmaf(x0.y, w[k+1], a0);
      a0 = fmaf(x0.z, w[k+2], a0);  a0 = fmaf(x0.w, w[k+3], a0);
      a1 = fmaf(x1.x, w[k+4], a1);  a1 = fmaf(x1.y, w[k+5], a1);
      a1 = fmaf(x1.z, w[k+6], a1);  a1 = fmaf(x1.w, w[k+7], a1);
      a2 = fmaf(x2.x, w[k+8], a2);  a2 = fmaf(x2.y, w[k+9], a2);
      a2 = fmaf(x2.z, w[k+10], a2); a2 = fmaf(x2.w, w[k+11], a2);
      a3 = fmaf(x3.x, w[k+12], a3); a3 = fmaf(x3.y, w[k+13], a3);
      a3 = fmaf(x3.z, w[k+14], a3); a3 = fmaf(x3.w, w[k+15], a3);
    }
    gp[(size_t)r * 256] = f2bf(bias + (a0 + a1) + (a2 + a3));
  }
}

// ---------------- persistent LSTM: one wave/stream, weights in swizzled LDS ---
#if __has_builtin(__builtin_amdgcn_fdot2)
#define HAVE_DOT2 1
typedef __fp16 half2v __attribute__((ext_vector_type(2)));
__device__ __forceinline__ half2v u2h(uint_t u) { union { uint_t u; half2v h; } x; x.u = u; return x.h; }
__device__ __forceinline__ uint_t h2u(half2v h) { union { uint_t u; half2v h; } x; x.h = h; return x.u; }
#else
#define HAVE_DOT2 0
#endif

#define GRP_ 4   // steps per prefetch group

__global__ __launch_bounds__(64, 1) void k_lstm3(
    const ushort_t* __restrict__ gx,
    const float* __restrict__ WhhF, const float* __restrict__ WhhB,
    float* __restrict__ y) {
  const int b   = blockIdx.x & 63;
  const int dir = blockIdx.x >> 6;
  const int l   = threadIdx.x;
  const float* Whh = dir ? WhhB : WhhF;

#if HAVE_DOT2
  // LDS weights: f16-packed, row = gate-row (g*64+l), 128 B/row, XOR-swizzled
  // byte(g,l,j) = ((g*64+l)<<7) + ((j<<4) ^ ((l&7)<<4)),  j = 0..7 (16B chunks)
  __shared__ __align__(16) uint_t wl[4 * 64 * 32];     // 32 KB
  __shared__ __align__(16) float hs[64];
  char* wb = (char*)wl;
  const int swz = (l & 7) << 4;

#pragma unroll
  for (int g4 = 0; g4 < 4; ++g4) {
#pragma unroll
    for (int j = 0; j < 8; ++j) {
      const float* src = &Whh[(size_t)(g4 * 64 + l) * 64 + j * 8];
      float4 f0 = *reinterpret_cast<const float4*>(src);
      float4 f1 = *reinterpret_cast<const float4*>(src + 4);
      uint4 w4;
      w4.x = h2u(__builtin_amdgcn_cvt_pkrtz(f0.x, f0.y));
      w4.y = h2u(__builtin_amdgcn_cvt_pkrtz(f0.z, f0.w));
      w4.z = h2u(__builtin_amdgcn_cvt_pkrtz(f1.x, f1.y));
      w4.w = h2u(__builtin_amdgcn_cvt_pkrtz(f1.z, f1.w));
      *reinterpret_cast<uint4*>(wb + (((g4 * 64 + l) << 7) + ((j << 4) ^ swz))) = w4;
    }
  }
  hs[l] = 0.f;     // same-wave in-order DS: no barrier needed (1 wave/block)
  float c = 0.f;

  const long stride = dir ? -256 : 256;
  const long ystr   = dir ? -128 : 128;
  const int s0 = dir ? N_ - 1 : 0;
  const ushort_t* p = gx + ((size_t)dir * NN_ + (size_t)b * N_ + s0) * 256 + l;
  float* yp = y + ((size_t)b * N_ + s0) * 128 + (size_t)dir * 64 + l;

  float zc[GRP_][4], zn[GRP_][4];
#pragma unroll
  for (int i = 0; i < GRP_; ++i)
#pragma unroll
    for (int g4 = 0; g4 < 4; ++g4)
      zc[i][g4] = bf2f(p[i * stride + g4 * 64]);
  p += GRP_ * stride;

  for (int g = 0; g < N_ / GRP_; ++g) {
    if (g != N_ / GRP_ - 1) {
#pragma unroll
      for (int i = 0; i < GRP_; ++i)
#pragma unroll
        for (int g4 = 0; g4 < 4; ++g4)
          zn[i][g4] = bf2f(p[i * stride + g4 * 64]);
    }
    p += GRP_ * stride;

    float yv[GRP_];
#pragma unroll
    for (int i = 0; i < GRP_; ++i) {
      // h -> f16 pairs (broadcast LDS reads; hs written by this wave last step)
      half2v hp[32];
#pragma unroll
      for (int k4 = 0; k4 < 16; ++k4) {
        float4 hv = *reinterpret_cast<const float4*>(&hs[4 * k4]);
        hp[2 * k4]     = __builtin_amdgcn_cvt_pkrtz(hv.x, hv.y);
        hp[2 * k4 + 1] = __builtin_amdgcn_cvt_pkrtz(hv.z, hv.w);
      }
      float acc[4];
#pragma unroll
      for (int g4 = 0; g4 < 4; ++g4) {
        float a = zc[i][g4];
        const int rowb = (g4 * 64 + l) << 7;
#pragma unroll
        for (int j = 0; j < 8; ++j) {
          uint4 wv = *reinterpret_cast<const uint4*>(wb + (rowb + ((j << 4) ^ swz)));
          a = __builtin_amdgcn_fdot2(u2h(wv.x), hp[4 * j],     a, false);
          a = __builtin_amdgcn_fdot2(u2h(wv.y), hp[4 * j + 1], a, false);
          a = __builtin_amdgcn_fdot2(u2h(wv.z), hp[4 * j + 2], a, false);
          a = __builtin_amdgcn_fdot2(u2h(wv.w), hp[4 * j + 3], a, false);
        }
        acc[g4] = a;
      }
      float si_ = __fdividef(1.f, 1.f + __expf(-acc[0]));
      float sf  = __fdividef(1.f, 1.f + __expf(-acc[1]));
      float tg  = 1.f - __fdividef(2.f, __expf(2.f * acc[2]) + 1.f);
      float so  = __fdividef(1.f, 1.f + __expf(-acc[3]));
      c = sf * c + si_ * tg;
      float tc = 1.f - __fdividef(2.f, __expf(2.f * c) + 1.f);
      float hh = so * tc;
      hs[l] = hh;
      yv[i] = hh;
    }
#pragma unroll
    for (int i = 0; i < GRP_; ++i) yp[(long)i * ystr] = yv[i];
    yp += GRP_ * ystr;
#pragma unroll
    for (int i = 0; i < GRP_; ++i)
#pragma unroll
      for (int g4 = 0; g4 < 4; ++g4) zc[i][g4] = zn[i][g4];
  }
#else
  // f32 fallback (no dot2): register weights, as round 7
  float wf[256];
#pragma unroll
  for (int i = 0; i < 64; ++i) {
    const int g4 = i >> 4, k4 = i & 15;
    float4 f4 = *reinterpret_cast<const float4*>(&Whh[(size_t)(g4 * 64 + l) * 64 + 4 * k4]);
    wf[g4 * 64 + 4 * k4 + 0] = f4.x; wf[g4 * 64 + 4 * k4 + 1] = f4.y;
    wf[g4 * 64 + 4 * k4 + 2] = f4.z; wf[g4 * 64 + 4 * k4 + 3] = f4.w;
  }
  __shared__ __align__(16) float hs[64];
  hs[l] = 0.f;
  float c = 0.f;
  const long stride = dir ? -256 : 256;
  const long ystr   = dir ? -128 : 128;
  const int s0 = dir ? N_ - 1 : 0;
  const ushort_t* p = gx + ((size_t)dir * NN_ + (size_t)b * N_ + s0) * 256 + l;
  float* yp = y + ((size_t)b * N_ + s0) * 128 + (size_t)dir * 64 + l;
  for (int s = 0; s < N_; ++s) {
    float acc[4];
#pragma unroll
    for (int g4 = 0; g4 < 4; ++g4) acc[g4] = bf2f(p[g4 * 64]);
    p += stride;
#pragma unroll
    for (int k4 = 0; k4 < 16; ++k4) {
      float4 hv = *reinterpret_cast<const float4*>(&hs[4 * k4]);
#pragma unroll
      for (int g4 = 0; g4 < 4; ++g4) {
        acc[g4] = fmaf(hv.x, wf[g4*64+4*k4+0], acc[g4]);
        acc[g4] = fmaf(hv.y, wf[g4*64+4*k4+1], acc[g4]);
        acc[g4] = fmaf(hv.z, wf[g4*64+4*k4+2], acc[g4]);
        acc[g4] = fmaf(hv.w, wf[g4*64+4*k4+3], acc[g4]);
      }
    }
    float si_ = __fdividef(1.f, 1.f + __expf(-acc[0]));
    float sf  = __fdividef(1.f, 1.f + __expf(-acc[1]));
    float tg  = 1.f - __fdividef(2.f, __expf(2.f * acc[2]) + 1.f);
    float so  = __fdividef(1.f, 1.f + __expf(-acc[3]));
    c = sf * c + si_ * tg;
    float tc = 1.f - __fdividef(2.f, __expf(2.f * c) + 1.f);
    float hh = so * tc;
    hs[l] = hh;
    *yp = hh;
    yp += ystr;
  }
#endif
}

// ---------------- fallback persistent LSTM (round-3 version, safe path) -------
__global__ __launch_bounds__(256) void k_lstm(
    const float* __restrict__ h2raw, const float* __restrict__ b2,
    const float* __restrict__ WihF, const float* __restrict__ WhhF,
    const float* __restrict__ bihF, const float* __restrict__ bhhF,
    const float* __restrict__ WihB, const float* __restrict__ WhhB,
    const float* __restrict__ bihB, const float* __restrict__ bhhB,
    float* __restrict__ y) {
  const int b   = blockIdx.x & 63;
  const int dir = blockIdx.x >> 6;
  const float* Wih = dir ? WihB : WihF;
  const float* Whh = dir ? WhhB : WhhF;
  const float* bih = dir ? bihB : bihF;
  const float* bhh = dir ? bhhB : bhhF;
  const int j = threadIdx.x;

  float wih[64], whh[64];
#pragma unroll
  for (int k = 0; k < 64; k += 4) {
    *reinterpret_cast<float4*>(&wih[k]) = *reinterpret_cast<const float4*>(&Wih[j * 64 + k]);
    *reinterpret_cast<float4*>(&whh[k]) = *reinterpret_cast<const float4*>(&Whh[j * 64 + k]);
  }
  const float bias = bih[j] + bhh[j];
  const float b2j = (j < 64) ? b2[j] : 0.f;

  __shared__ __align__(16) float xbuf[64];
  __shared__ __align__(16) float hbuf[64];
  __shared__ float gbuf[256];
  float c = 0.f;
  if (j < 64) hbuf[j] = 0.f;

  float xc = 0.f, xn = 0.f;
  if (j < 64) {
    const int s0 = dir ? N_ - 1 : 0;
    const int s1 = dir ? N_ - 2 : 1;
    xc = h2raw[((size_t)b * N_ + s0) * 64 + j];
    xn = h2raw[((size_t)b * N_ + s1) * 64 + j];
  }

  for (int si = 0; si < N_; ++si) {
    const int s = dir ? (N_ - 1 - si) : si;
    const size_t vrow = (size_t)b * N_ + s;
    if (j < 64) xbuf[j] = fmaxf(xc + b2j, 0.f);
    LBAR();

    float xp = 0.f;
    {
      int si2 = si + 2; if (si2 >= N_) si2 = N_ - 1;
      const int s2 = dir ? (N_ - 1 - si2) : si2;
      if (j < 64) xp = h2raw[((size_t)b * N_ + s2) * 64 + j];
    }

    float a0 = 0.f, a1 = 0.f, a2 = 0.f, a3 = 0.f;
#pragma unroll
    for (int k = 0; k < 64; k += 16) {
      float4 xv0 = *reinterpret_cast<const float4*>(&xbuf[k]);
      float4 hv0 = *reinterpret_cast<const float4*>(&hbuf[k]);
      a0 = fmaf(xv0.x, wih[k+0], a0); a0 = fmaf(hv0.x, whh[k+0], a0);
      a0 = fmaf(xv0.y, wih[k+1], a0); a0 = fmaf(hv0.y, whh[k+1], a0);
      a0 = fmaf(xv0.z, wih[k+2], a0); a0 = fmaf(hv0.z, whh[k+2], a0);
      a0 = fmaf(xv0.w, wih[k+3], a0); a0 = fmaf(hv0.w, whh[k+3], a0);
      float4 xv1 = *reinterpret_cast<const float4*>(&xbuf[k+4]);
      float4 hv1 = *reinterpret_cast<const float4*>(&hbuf[k+4]);
      a1 = fmaf(xv1.x, wih[k+4], a1); a1 = fmaf(hv1.x, whh[k+4], a1);
      a1 = fmaf(xv1.y, wih[k+5], a1); a1 = fmaf(hv1.y, whh[k+5], a1);
      a1 = fmaf(xv1.z, wih[k+6], a1); a1 = fmaf(hv1.z, whh[k+6], a1);
      a1 = fmaf(xv1.w, wih[k+7], a1); a1 = fmaf(hv1.w, whh[k+7], a1);
      float4 xv2 = *reinterpret_cast<const float4*>(&xbuf[k+8]);
      float4 hv2 = *reinterpret_cast<const float4*>(&hbuf[k+8]);
      a2 = fmaf(xv2.x, wih[k+8], a2); a2 = fmaf(hv2.x, whh[k+8], a2);
      a2 = fmaf(xv2.y, wih[k+9], a2); a2 = fmaf(hv2.y, whh[k+9], a2);
      a2 = fmaf(xv2.z, wih[k+10], a2); a2 = fmaf(hv2.z, whh[k+10], a2);
      a2 = fmaf(xv2.w, wih[k+11], a2); a2 = fmaf(hv2.w, whh[k+11], a2);
      float4 xv3 = *reinterpret_cast<const float4*>(&xbuf[k+12]);
      float4 hv3 = *reinterpret_cast<const float4*>(&hbuf[k+12]);
      a3 = fmaf(xv3.x, wih[k+12], a3); a3 = fmaf(hv3.x, whh[k+12], a3);
      a3 = fmaf(xv3.y, wih[k+13], a3); a3 = fmaf(hv3.y, whh[k+13], a3);
      a3 = fmaf(xv3.z, wih[k+14], a3); a3 = fmaf(hv3.z, whh[k+14], a3);
      a3 = fmaf(xv3.w, wih[k+15], a3); a3 = fmaf(hv3.w, whh[k+15], a3);
    }
    gbuf[j] = bias + (a0 + a1) + (a2 + a3);
    LBAR();

    if (j < 64) {
      float gi = gbuf[j], gf = gbuf[64 + j], gg = gbuf[128 + j], go = gbuf[192 + j];
      float si_ = __fdividef(1.f, 1.f + __expf(-gi));
      float sf  = __fdividef(1.f, 1.f + __expf(-gf));
      float so  = __fdividef(1.f, 1.f + __expf(-go));
      float tg  = 1.f - __fdividef(2.f, __expf(2.f * gg) + 1.f);
      c = sf * c + si_ * tg;
      float tc = 1.f - __fdividef(2.f, __expf(2.f * c) + 1.f);
      float hh = so * tc;
      hbuf[j] = hh;
      y[vrow * 128 + (size_t)dir * 64 + j] = hh;
    }
    xc = xn; xn = xp;
  }
}

// ---------------- decoder + masked MSE (LDS-staged y rows) ----------------
__global__ __launch_bounds__(256) void k_decoder(
    const float* __restrict__ y, const float* __restrict__ x,
    const float* __restrict__ mask, const float* __restrict__ Wd,
    const float* __restrict__ bd, float* __restrict__ out,
    float* __restrict__ accum) {
  __shared__ float ys[16 * 132];           // 16 rows, padded to 132 floats
  const int tid = threadIdx.x;
  const size_t base = (size_t)blockIdx.x * 2048;
#pragma unroll
  for (int u = 0; u < 2; ++u) {
    int idx = u * 1024 + tid * 4;
    *reinterpret_cast<float4*>(&ys[(idx >> 7) * 132 + (idx & 127)]) =
        *reinterpret_cast<const float4*>(&y[base + idx]);
  }
  __syncthreads();
  size_t v = (size_t)blockIdx.x * 16 + (tid >> 4);
  int f = tid & 15;
  const float* yr = &ys[(tid >> 4) * 132];
  float acc = bd[f];
#pragma unroll
  for (int jj = 0; jj < 128; jj += 4) {
    float4 yv = *reinterpret_cast<const float4*>(&yr[jj]);
    float4 wv = *reinterpret_cast<const float4*>(&Wd[f * 128 + jj]);
    acc = fmaf(yv.x, wv.x, acc); acc = fmaf(yv.y, wv.y, acc);
    acc = fmaf(yv.z, wv.z, acc); acc = fmaf(yv.w, wv.w, acc);
  }
  size_t o = v * 16 + f;
  float xv = x[o], m = mask[o];
  float d = acc - xv;
  out[o] = (m != 0.f) ? xv : acc;
  float num = m * d * d;
  float den = m;
#pragma unroll
  for (int off = 32; off > 0; off >>= 1) {
    num += __shfl_down(num, off);
    den += __shfl_down(den, off);
  }
  if ((tid & 63) == 0) {
    unsafeAtomicAdd(&accum[0], num);
    unsafeAtomicAdd(&accum[1], den);
  }
}

__global__ void k_loss(const float* __restrict__ accum, float* __restrict__ out_loss) {
  if (threadIdx.x == 0) out_loss[0] = accum[0] / (accum[1] + 1e-8f);
}

// ---------------- launch ----------------
extern "C" void kernel_launch(void* const* d_in, const int* in_sizes, int n_in,
                              void* d_out, int out_size, void* d_ws, size_t ws_size,
                              hipStream_t stream) {
  const float* x    = (const float*)d_in[0];
  const int*   ei   = (const int*)d_in[1];   // row = ei, col = ei + E_
  const float* mask = (const float*)d_in[2];
  const float* W1 = (const float*)d_in[3];
  const float* b1 = (const float*)d_in[4];
  const float* W2 = (const float*)d_in[5];
  const float* b2 = (const float*)d_in[6];
  const float* WihF = (const float*)d_in[7];
  const float* WhhF = (const float*)d_in[8];
  const float* bihF = (const float*)d_in[9];
  const float* bhhF = (const float*)d_in[10];
  const float* WihB = (const float*)d_in[11];
  const float* WhhB = (const float*)d_in[12];
  const float* bihB = (const float*)d_in[13];
  const float* bhhB = (const float*)d_in[14];
  const float* Wd = (const float*)d_in[15];
  const float* bd = (const float*)d_in[16];
  float* out = (float*)d_out;

  // layout: dinv | accum | Y(67M) | C(33.5M) | A(33.5M, gx overlays A +134M)
  float* dinv  = (float*)d_ws;
  float* accum = dinv + NN_;
  float* Y     = accum + 64;
  float* C     = Y + (size_t)NN_ * 128;
  float* A     = C + (size_t)NN_ * 64;
  ushort_t* gx = (ushort_t*)A;
  // sort scratch overlays Y (dead until LSTM writes it)
  int*    srow   = (int*)Y;
  uint_t* cnt    = (uint_t*)(srow + E_);
  uint_t* start  = cnt + NN_;
  uint_t* cursor = start + NN_ + 1;
  uint_t* bsum   = cursor + NN_;

  size_t need = ((char*)A - (char*)d_ws) + 2ull * NN_ * 256 * sizeof(ushort_t);
  bool use_gx = ws_size >= need;

  // ---- degree + col-sort ----
  k_zero<<<NN_ / 256, 256, 0, stream>>>(cnt, accum);
  k_hist<<<E_ / 256, 256, 0, stream>>>(ei + E_, cnt);
  k_dinvc<<<NN_ / 256, 256, 0, stream>>>(cnt, dinv);
  k_bsum<<<512, 256, 0, stream>>>(cnt, bsum);
  k_scan512<<<1, 512, 0, stream>>>(bsum);
  k_scanadd<<<512, 256, 0, stream>>>(cnt, bsum, start, cursor);
  k_place<<<E_ / 256, 256, 0, stream>>>(ei, ei + E_, cursor, srow);

  // ---- GCN layer 1 ----
  k_gemm<FIN_, false><<<NN_ / 4, 256, 0, stream>>>(x, W1, nullptr, dinv, A);
  k_colagg<<<NN_ / 4, 256, 0, stream>>>(srow, start, dinv, A, C);

  // ---- GCN layer 2 ----
  k_gemm<64, true><<<NN_ / 4, 256, 0, stream>>>(C, W2, b1, dinv, A);
  k_colagg<<<NN_ / 4, 256, 0, stream>>>(srow, start, dinv, A, C);

  if (use_gx) {
    k_gates<<<2 * (NN_ / 64), 256, 0, stream>>>(C, b2, WihF, bihF, bhhF,
                                                WihB, bihB, bhhB, gx);
    k_lstm3<<<128, 64, 0, stream>>>(gx, WhhF, WhhB, Y);
  } else {
    k_lstm<<<128, 256, 0, stream>>>(C, b2, WihF, WhhF, bihF, bhhF,
                                    WihB, WhhB, bihB, bhhB, Y);
  }

  k_decoder<<<NN_ / 16, 256, 0, stream>>>(Y, x, mask, Wd, bd, out, accum);
  k_loss<<<1, 64, 0, stream>>>(accum, out + (size_t)NN_ * FIN_);
}

// Round 9
// 5032.494 us; speedup vs baseline: 1.0248x; 1.0248x over previous
//
#include <hip/hip_runtime.h>

#define NN_ 131072      // T*N
#define T_ 64
#define N_ 2048
#define E_ 2097152
#define FIN_ 16

typedef unsigned short ushort_t;
typedef unsigned int uint_t;

// memory-clobber LDS barrier (fallback kernel only)
#define LBAR() asm volatile("s_waitcnt lgkmcnt(0)\n\ts_barrier" ::: "memory")

__device__ __forceinline__ float bf2f(ushort_t u) {
  return __uint_as_float(((uint_t)u) << 16);
}
__device__ __forceinline__ ushort_t f2bf(float f) {
  uint_t b = __float_as_uint(f);
  b += 0x7fffu + ((b >> 16) & 1u);   // round-to-nearest-even
  return (ushort_t)(b >> 16);
}

// ---------------- zero cnt + accum ----------------
__global__ void k_zero(uint_t* __restrict__ cnt, float* __restrict__ accum) {
  int i = blockIdx.x * 256 + threadIdx.x;
  if (i < NN_) cnt[i] = 0u;
  if (i < 2) accum[i] = 0.f;
}

// ---------------- histogram of col ----------------
__global__ void k_hist(const int* __restrict__ col, uint_t* __restrict__ cnt) {
  int e = blockIdx.x * 256 + threadIdx.x;
  atomicAdd(&cnt[col[e]], 1u);
}

// ---------------- dinv from counts (+1 self loop) ----------------
__global__ void k_dinvc(const uint_t* __restrict__ cnt, float* __restrict__ dinv) {
  int v = blockIdx.x * 256 + threadIdx.x;
  dinv[v] = rsqrtf((float)cnt[v] + 1.f);
}

// ---------------- per-256-chunk sums ----------------
__global__ void k_bsum(const uint_t* __restrict__ cnt, uint_t* __restrict__ bsum) {
  int t = threadIdx.x;
  uint_t v = cnt[blockIdx.x * 256 + t];
  for (int off = 32; off; off >>= 1) v += __shfl_down(v, off);
  __shared__ uint_t s4[4];
  if ((t & 63) == 0) s4[t >> 6] = v;
  __syncthreads();
  if (t == 0) bsum[blockIdx.x] = s4[0] + s4[1] + s4[2] + s4[3];
}

// ---------------- exclusive scan of 512 chunk sums (1 block) ----------------
__global__ void k_scan512(uint_t* __restrict__ bsum) {
  __shared__ uint_t sd[512];
  int t = threadIdx.x;
  uint_t v = bsum[t];
  sd[t] = v;
  __syncthreads();
  for (int off = 1; off < 512; off <<= 1) {
    uint_t x = (t >= off) ? sd[t - off] : 0u;
    __syncthreads();
    sd[t] += x;
    __syncthreads();
  }
  bsum[t] = sd[t] - v;   // exclusive
}

// ---------------- per-chunk exclusive scan + chunk offset ----------------
__global__ void k_scanadd(const uint_t* __restrict__ cnt, const uint_t* __restrict__ bsum,
                          uint_t* __restrict__ start, uint_t* __restrict__ cursor) {
  int t = threadIdx.x;
  int i = blockIdx.x * 256 + t;
  uint_t v = cnt[i];
  __shared__ uint_t sd[256];
  sd[t] = v;
  __syncthreads();
  for (int off = 1; off < 256; off <<= 1) {
    uint_t x = (t >= off) ? sd[t - off] : 0u;
    __syncthreads();
    sd[t] += x;
    __syncthreads();
  }
  uint_t excl = sd[t] - v + bsum[blockIdx.x];
  start[i] = excl;
  cursor[i] = excl;
  if (i == NN_ - 1) start[NN_] = E_;
}

// ---------------- counting-sort placement: srow grouped by col ----------------
__global__ void k_place(const int* __restrict__ row, const int* __restrict__ col,
                        uint_t* __restrict__ cursor, int* __restrict__ srow) {
  int e = blockIdx.x * 256 + threadIdx.x;
  int c = col[e];
  uint_t pos = atomicAdd(&cursor[c], 1u);
  srow[pos] = row[e];
}

// ---------------- GEMM (NN x K) @ (K x 64), writes dinv-prescaled rows -------
template <int K, bool RELU_IN>
__global__ void k_gemm(const float* __restrict__ X, const float* __restrict__ W,
                       const float* __restrict__ bin, const float* __restrict__ dinv,
                       float* __restrict__ xws) {
  __shared__ float xs[4 * K];
  const int tid = threadIdx.x;
  const int v0 = blockIdx.x * 4;
  for (int t = tid; t < 4 * K; t += 256) {
    float v = X[(size_t)v0 * K + t];
    if (RELU_IN) v = fmaxf(v + bin[t & (K - 1)], 0.f);
    xs[t] = v;
  }
  __syncthreads();
  const int v = v0 + (tid >> 6);
  const int j = tid & 63;
  const float* xr = &xs[(tid >> 6) * K];
  float acc = 0.f;
#pragma unroll
  for (int k = 0; k < K; ++k) acc = fmaf(xr[k], W[k * 64 + j], acc);
  xws[(size_t)v * 64 + j] = dinv[v] * acc;
}

// ---------------- column-gather aggregation (no atomics) ----------------------
__global__ void k_colagg(const int* __restrict__ srow, const uint_t* __restrict__ start,
                         const float* __restrict__ dinv, const float* __restrict__ xws,
                         float* __restrict__ agg) {
  int c = blockIdx.x * 4 + (threadIdx.x >> 6);
  int lane = threadIdx.x & 63;
  uint_t s = start[c], e = start[c + 1];
  float acc = xws[(size_t)c * 64 + lane];      // self loop
  for (uint_t i = s; i < e; ++i) {
    int r = srow[i];
    acc += xws[(size_t)r * 64 + lane];
  }
  agg[(size_t)c * 64 + lane] = dinv[c] * acc;
}

// ---------------- gate-preactivation GEMM (bf16 out) --------------------------
__global__ __launch_bounds__(256) void k_gates(
    const float* __restrict__ A, const float* __restrict__ b2,
    const float* __restrict__ WihF, const float* __restrict__ bihF,
    const float* __restrict__ bhhF,
    const float* __restrict__ WihB, const float* __restrict__ bihB,
    const float* __restrict__ bhhB,
    ushort_t* __restrict__ gx) {
  const int dir = blockIdx.x >> 11;
  const int v0 = (blockIdx.x & 2047) * 64;
  const float* Wih = dir ? WihB : WihF;
  const float* bih = dir ? bihB : bihF;
  const float* bhh = dir ? bhhB : bhhF;
  const int t = threadIdx.x;

  float w[64];
#pragma unroll
  for (int k = 0; k < 64; k += 4)
    *reinterpret_cast<float4*>(&w[k]) = *reinterpret_cast<const float4*>(&Wih[t * 64 + k]);
  const float bias = bih[t] + bhh[t];

  __shared__ float xs[64 * 64];
#pragma unroll
  for (int u = 0; u < 16; ++u) {
    int idx = u * 256 + t;
    xs[idx] = fmaxf(A[(size_t)v0 * 64 + idx] + b2[idx & 63], 0.f);
  }
  __syncthreads();

  ushort_t* gp = gx + ((size_t)(dir ? NN_ : 0) + v0) * 256 + t;
  for (int r = 0; r < 64; ++r) {
    const float* xr = &xs[r * 64];
    float a0 = 0.f, a1 = 0.f, a2 = 0.f, a3 = 0.f;
#pragma unroll
    for (int k = 0; k < 64; k += 16) {
      float4 x0 = *reinterpret_cast<const float4*>(&xr[k]);
      float4 x1 = *reinterpret_cast<const float4*>(&xr[k + 4]);
      float4 x2 = *reinterpret_cast<const float4*>(&xr[k + 8]);
      float4 x3 = *reinterpret_cast<const float4*>(&xr[k + 12]);
      a0 = fmaf(x0.x, w[k+0], a0);  a0 = fmaf(x0.y, w[k+1], a0);
      a0 = fmaf(x0.z, w[k+2], a0);  a0 = fmaf(x0.w, w[k+3], a0);
      a1 = fmaf(x1.x, w[k+4], a1);  a1 = fmaf(x1.y, w[k+5], a1);
      a1 = fmaf(x1.z, w[k+6], a1);  a1 = fmaf(x1.w, w[k+7], a1);
      a2 = fmaf(x2.x, w[k+8], a2);  a2 = fmaf(x2.y, w[k+9], a2);
      a2 = fmaf(x2.z, w[k+10], a2); a2 = fmaf(x2.w, w[k+11], a2);
      a3 = fmaf(x3.x, w[k+12], a3); a3 = fmaf(x3.y, w[k+13], a3);
      a3 = fmaf(x3.z, w[k+14], a3); a3 = fmaf(x3.w, w[k+15], a3);
    }
    gp[(size_t)r * 256] = f2bf(bias + (a0 + a1) + (a2 + a3));
  }
}

// ---------------- persistent LSTM: one wave/stream, weights in LDS ------------
// Transposed (chunk-major) layout: wlds[(g4*8+j)*64 + lane] holds the 16B chunk
// j of gate-row (g4*64+lane). Lane-contiguous 16B => conflict-free b128 R/W.
#if __has_builtin(__builtin_amdgcn_fdot2)
#define HAVE_DOT2 1
typedef __fp16 half2v __attribute__((ext_vector_type(2)));
__device__ __forceinline__ half2v u2h(uint_t u) { union { uint_t u; half2v h; } x; x.u = u; return x.h; }
__device__ __forceinline__ uint_t h2u(half2v h) { union { uint_t u; half2v h; } x; x.h = h; return x.u; }
#else
#define HAVE_DOT2 0
#endif

#define GRP_ 4   // steps per prefetch group

__global__ __launch_bounds__(64, 1) void k_lstm3(
    const ushort_t* __restrict__ gx,
    const float* __restrict__ WhhF, const float* __restrict__ WhhB,
    float* __restrict__ y) {
  const int b   = blockIdx.x & 63;
  const int dir = blockIdx.x >> 6;
  const int l   = threadIdx.x;
  const float* Whh = dir ? WhhB : WhhF;

#if HAVE_DOT2
  __shared__ __align__(16) uint4 wlds[4 * 8 * 64];     // 32 KB, chunk-major
  __shared__ __align__(16) float hs[64];

#pragma unroll
  for (int g4 = 0; g4 < 4; ++g4) {
#pragma unroll
    for (int j = 0; j < 8; ++j) {
      const float* src = &Whh[(size_t)(g4 * 64 + l) * 64 + j * 8];
      float4 f0 = *reinterpret_cast<const float4*>(src);
      float4 f1 = *reinterpret_cast<const float4*>(src + 4);
      uint4 w4;
      w4.x = h2u(__builtin_amdgcn_cvt_pkrtz(f0.x, f0.y));
      w4.y = h2u(__builtin_amdgcn_cvt_pkrtz(f0.z, f0.w));
      w4.z = h2u(__builtin_amdgcn_cvt_pkrtz(f1.x, f1.y));
      w4.w = h2u(__builtin_amdgcn_cvt_pkrtz(f1.z, f1.w));
      wlds[(g4 * 8 + j) * 64 + l] = w4;                // lane-contiguous write
    }
  }
  hs[l] = 0.f;     // same-wave in-order DS: no barrier needed (1 wave/block)
  float c = 0.f;

  const long stride = dir ? -256 : 256;
  const long ystr   = dir ? -128 : 128;
  const int s0 = dir ? N_ - 1 : 0;
  const ushort_t* p = gx + ((size_t)dir * NN_ + (size_t)b * N_ + s0) * 256 + l;
  float* yp = y + ((size_t)b * N_ + s0) * 128 + (size_t)dir * 64 + l;

  float zc[GRP_][4], zn[GRP_][4];
#pragma unroll
  for (int i = 0; i < GRP_; ++i)
#pragma unroll
    for (int g4 = 0; g4 < 4; ++g4)
      zc[i][g4] = bf2f(p[i * stride + g4 * 64]);
  p += GRP_ * stride;

  for (int g = 0; g < N_ / GRP_; ++g) {
    if (g != N_ / GRP_ - 1) {
#pragma unroll
      for (int i = 0; i < GRP_; ++i)
#pragma unroll
        for (int g4 = 0; g4 < 4; ++g4)
          zn[i][g4] = bf2f(p[i * stride + g4 * 64]);
    }
    p += GRP_ * stride;

    float yv[GRP_];
#pragma unroll
    for (int i = 0; i < GRP_; ++i) {
      // h -> f16 pairs (broadcast LDS reads; hs written by this wave last step)
      half2v hp[32];
#pragma unroll
      for (int k4 = 0; k4 < 16; ++k4) {
        float4 hv = *reinterpret_cast<const float4*>(&hs[4 * k4]);
        hp[2 * k4]     = __builtin_amdgcn_cvt_pkrtz(hv.x, hv.y);
        hp[2 * k4 + 1] = __builtin_amdgcn_cvt_pkrtz(hv.z, hv.w);
      }
      float acc[4];
#pragma unroll
      for (int g4 = 0; g4 < 4; ++g4) {
        float a = zc[i][g4];
#pragma unroll
        for (int j = 0; j < 8; ++j) {
          uint4 wv = wlds[(g4 * 8 + j) * 64 + l];      // conflict-free b128
          a = __builtin_amdgcn_fdot2(u2h(wv.x), hp[4 * j],     a, false);
          a = __builtin_amdgcn_fdot2(u2h(wv.y), hp[4 * j + 1], a, false);
          a = __builtin_amdgcn_fdot2(u2h(wv.z), hp[4 * j + 2], a, false);
          a = __builtin_amdgcn_fdot2(u2h(wv.w), hp[4 * j + 3], a, false);
        }
        acc[g4] = a;
      }
      float si_ = __fdividef(1.f, 1.f + __expf(-acc[0]));
      float sf  = __fdividef(1.f, 1.f + __expf(-acc[1]));
      float tg  = 1.f - __fdividef(2.f, __expf(2.f * acc[2]) + 1.f);
      float so  = __fdividef(1.f, 1.f + __expf(-acc[3]));
      c = sf * c + si_ * tg;
      float tc = 1.f - __fdividef(2.f, __expf(2.f * c) + 1.f);
      float hh = so * tc;
      hs[l] = hh;
      yv[i] = hh;
    }
#pragma unroll
    for (int i = 0; i < GRP_; ++i) yp[(long)i * ystr] = yv[i];
    yp += GRP_ * ystr;
#pragma unroll
    for (int i = 0; i < GRP_; ++i)
#pragma unroll
      for (int g4 = 0; g4 < 4; ++g4) zc[i][g4] = zn[i][g4];
  }
#else
  // f32 fallback (no dot2): register weights
  float wf[256];
#pragma unroll
  for (int i = 0; i < 64; ++i) {
    const int g4 = i >> 4, k4 = i & 15;
    float4 f4 = *reinterpret_cast<const float4*>(&Whh[(size_t)(g4 * 64 + l) * 64 + 4 * k4]);
    wf[g4 * 64 + 4 * k4 + 0] = f4.x; wf[g4 * 64 + 4 * k4 + 1] = f4.y;
    wf[g4 * 64 + 4 * k4 + 2] = f4.z; wf[g4 * 64 + 4 * k4 + 3] = f4.w;
  }
  __shared__ __align__(16) float hs[64];
  hs[l] = 0.f;
  float c = 0.f;
  const long stride = dir ? -256 : 256;
  const long ystr   = dir ? -128 : 128;
  const int s0 = dir ? N_ - 1 : 0;
  const ushort_t* p = gx + ((size_t)dir * NN_ + (size_t)b * N_ + s0) * 256 + l;
  float* yp = y + ((size_t)b * N_ + s0) * 128 + (size_t)dir * 64 + l;
  for (int s = 0; s < N_; ++s) {
    float acc[4];
#pragma unroll
    for (int g4 = 0; g4 < 4; ++g4) acc[g4] = bf2f(p[g4 * 64]);
    p += stride;
#pragma unroll
    for (int k4 = 0; k4 < 16; ++k4) {
      float4 hv = *reinterpret_cast<const float4*>(&hs[4 * k4]);
#pragma unroll
      for (int g4 = 0; g4 < 4; ++g4) {
        acc[g4] = fmaf(hv.x, wf[g4*64+4*k4+0], acc[g4]);
        acc[g4] = fmaf(hv.y, wf[g4*64+4*k4+1], acc[g4]);
        acc[g4] = fmaf(hv.z, wf[g4*64+4*k4+2], acc[g4]);
        acc[g4] = fmaf(hv.w, wf[g4*64+4*k4+3], acc[g4]);
      }
    }
    float si_ = __fdividef(1.f, 1.f + __expf(-acc[0]));
    float sf  = __fdividef(1.f, 1.f + __expf(-acc[1]));
    float tg  = 1.f - __fdividef(2.f, __expf(2.f * acc[2]) + 1.f);
    float so  = __fdividef(1.f, 1.f + __expf(-acc[3]));
    c = sf * c + si_ * tg;
    float tc = 1.f - __fdividef(2.f, __expf(2.f * c) + 1.f);
    float hh = so * tc;
    hs[l] = hh;
    *yp = hh;
    yp += ystr;
  }
#endif
}

// ---------------- fallback persistent LSTM (round-3 version, safe path) -------
__global__ __launch_bounds__(256) void k_lstm(
    const float* __restrict__ h2raw, const float* __restrict__ b2,
    const float* __restrict__ WihF, const float* __restrict__ WhhF,
    const float* __restrict__ bihF, const float* __restrict__ bhhF,
    const float* __restrict__ WihB, const float* __restrict__ WhhB,
    const float* __restrict__ bihB, const float* __restrict__ bhhB,
    float* __restrict__ y) {
  const int b   = blockIdx.x & 63;
  const int dir = blockIdx.x >> 6;
  const float* Wih = dir ? WihB : WihF;
  const float* Whh = dir ? WhhB : WhhF;
  const float* bih = dir ? bihB : bihF;
  const float* bhh = dir ? bhhB : bhhF;
  const int j = threadIdx.x;

  float wih[64], whh[64];
#pragma unroll
  for (int k = 0; k < 64; k += 4) {
    *reinterpret_cast<float4*>(&wih[k]) = *reinterpret_cast<const float4*>(&Wih[j * 64 + k]);
    *reinterpret_cast<float4*>(&whh[k]) = *reinterpret_cast<const float4*>(&Whh[j * 64 + k]);
  }
  const float bias = bih[j] + bhh[j];
  const float b2j = (j < 64) ? b2[j] : 0.f;

  __shared__ __align__(16) float xbuf[64];
  __shared__ __align__(16) float hbuf[64];
  __shared__ float gbuf[256];
  float c = 0.f;
  if (j < 64) hbuf[j] = 0.f;

  float xc = 0.f, xn = 0.f;
  if (j < 64) {
    const int s0 = dir ? N_ - 1 : 0;
    const int s1 = dir ? N_ - 2 : 1;
    xc = h2raw[((size_t)b * N_ + s0) * 64 + j];
    xn = h2raw[((size_t)b * N_ + s1) * 64 + j];
  }

  for (int si = 0; si < N_; ++si) {
    const int s = dir ? (N_ - 1 - si) : si;
    const size_t vrow = (size_t)b * N_ + s;
    if (j < 64) xbuf[j] = fmaxf(xc + b2j, 0.f);
    LBAR();

    float xp = 0.f;
    {
      int si2 = si + 2; if (si2 >= N_) si2 = N_ - 1;
      const int s2 = dir ? (N_ - 1 - si2) : si2;
      if (j < 64) xp = h2raw[((size_t)b * N_ + s2) * 64 + j];
    }

    float a0 = 0.f, a1 = 0.f, a2 = 0.f, a3 = 0.f;
#pragma unroll
    for (int k = 0; k < 64; k += 16) {
      float4 xv0 = *reinterpret_cast<const float4*>(&xbuf[k]);
      float4 hv0 = *reinterpret_cast<const float4*>(&hbuf[k]);
      a0 = fmaf(xv0.x, wih[k+0], a0); a0 = fmaf(hv0.x, whh[k+0], a0);
      a0 = fmaf(xv0.y, wih[k+1], a0); a0 = fmaf(hv0.y, whh[k+1], a0);
      a0 = fmaf(xv0.z, wih[k+2], a0); a0 = fmaf(hv0.z, whh[k+2], a0);
      a0 = fmaf(xv0.w, wih[k+3], a0); a0 = fmaf(hv0.w, whh[k+3], a0);
      float4 xv1 = *reinterpret_cast<const float4*>(&xbuf[k+4]);
      float4 hv1 = *reinterpret_cast<const float4*>(&hbuf[k+4]);
      a1 = fmaf(xv1.x, wih[k+4], a1); a1 = fmaf(hv1.x, whh[k+4], a1);
      a1 = fmaf(xv1.y, wih[k+5], a1); a1 = fmaf(hv1.y, whh[k+5], a1);
      a1 = fmaf(xv1.z, wih[k+6], a1); a1 = fmaf(hv1.z, whh[k+6], a1);
      a1 = fmaf(xv1.w, wih[k+7], a1); a1 = fmaf(hv1.w, whh[k+7], a1);
      float4 xv2 = *reinterpret_cast<const float4*>(&xbuf[k+8]);
      float4 hv2 = *reinterpret_cast<const float4*>(&hbuf[k+8]);
      a2 = fmaf(xv2.x, wih[k+8], a2); a2 = fmaf(hv2.x, whh[k+8], a2);
      a2 = fmaf(xv2.y, wih[k+9], a2); a2 = fmaf(hv2.y, whh[k+9], a2);
      a2 = fmaf(xv2.z, wih[k+10], a2); a2 = fmaf(hv2.z, whh[k+10], a2);
      a2 = fmaf(xv2.w, wih[k+11], a2); a2 = fmaf(hv2.w, whh[k+11], a2);
      float4 xv3 = *reinterpret_cast<const float4*>(&xbuf[k+12]);
      float4 hv3 = *reinterpret_cast<const float4*>(&hbuf[k+12]);
      a3 = fmaf(xv3.x, wih[k+12], a3); a3 = fmaf(hv3.x, whh[k+12], a3);
      a3 = fmaf(xv3.y, wih[k+13], a3); a3 = fmaf(hv3.y, whh[k+13], a3);
      a3 = fmaf(xv3.z, wih[k+14], a3); a3 = fmaf(hv3.z, whh[k+14], a3);
      a3 = fmaf(xv3.w, wih[k+15], a3); a3 = fmaf(hv3.w, whh[k+15], a3);
    }
    gbuf[j] = bias + (a0 + a1) + (a2 + a3);
    LBAR();

    if (j < 64) {
      float gi = gbuf[j], gf = gbuf[64 + j], gg = gbuf[128 + j], go = gbuf[192 + j];
      float si_ = __fdividef(1.f, 1.f + __expf(-gi));
      float sf  = __fdividef(1.f, 1.f + __expf(-gf));
      float so  = __fdividef(1.f, 1.f + __expf(-go));
      float tg  = 1.f - __fdividef(2.f, __expf(2.f * gg) + 1.f);
      c = sf * c + si_ * tg;
      float tc = 1.f - __fdividef(2.f, __expf(2.f * c) + 1.f);
      float hh = so * tc;
      hbuf[j] = hh;
      y[vrow * 128 + (size_t)dir * 64 + j] = hh;
    }
    xc = xn; xn = xp;
  }
}

// ---------------- decoder + masked MSE (LDS-staged y rows) ----------------
__global__ __launch_bounds__(256) void k_decoder(
    const float* __restrict__ y, const float* __restrict__ x,
    const float* __restrict__ mask, const float* __restrict__ Wd,
    const float* __restrict__ bd, float* __restrict__ out,
    float* __restrict__ accum) {
  __shared__ float ys[16 * 132];           // 16 rows, padded to 132 floats
  const int tid = threadIdx.x;
  const size_t base = (size_t)blockIdx.x * 2048;
#pragma unroll
  for (int u = 0; u < 2; ++u) {
    int idx = u * 1024 + tid * 4;
    *reinterpret_cast<float4*>(&ys[(idx >> 7) * 132 + (idx & 127)]) =
        *reinterpret_cast<const float4*>(&y[base + idx]);
  }
  __syncthreads();
  size_t v = (size_t)blockIdx.x * 16 + (tid >> 4);
  int f = tid & 15;
  const float* yr = &ys[(tid >> 4) * 132];
  float acc = bd[f];
#pragma unroll
  for (int jj = 0; jj < 128; jj += 4) {
    float4 yv = *reinterpret_cast<const float4*>(&yr[jj]);
    float4 wv = *reinterpret_cast<const float4*>(&Wd[f * 128 + jj]);
    acc = fmaf(yv.x, wv.x, acc); acc = fmaf(yv.y, wv.y, acc);
    acc = fmaf(yv.z, wv.z, acc); acc = fmaf(yv.w, wv.w, acc);
  }
  size_t o = v * 16 + f;
  float xv = x[o], m = mask[o];
  float d = acc - xv;
  out[o] = (m != 0.f) ? xv : acc;
  float num = m * d * d;
  float den = m;
#pragma unroll
  for (int off = 32; off > 0; off >>= 1) {
    num += __shfl_down(num, off);
    den += __shfl_down(den, off);
  }
  if ((tid & 63) == 0) {
    unsafeAtomicAdd(&accum[0], num);
    unsafeAtomicAdd(&accum[1], den);
  }
}

__global__ void k_loss(const float* __restrict__ accum, float* __restrict__ out_loss) {
  if (threadIdx.x == 0) out_loss[0] = accum[0] / (accum[1] + 1e-8f);
}

// ---------------- launch ----------------
extern "C" void kernel_launch(void* const* d_in, const int* in_sizes, int n_in,
                              void* d_out, int out_size, void* d_ws, size_t ws_size,
                              hipStream_t stream) {
  const float* x    = (const float*)d_in[0];
  const int*   ei   = (const int*)d_in[1];   // row = ei, col = ei + E_
  const float* mask = (const float*)d_in[2];
  const float* W1 = (const float*)d_in[3];
  const float* b1 = (const float*)d_in[4];
  const float* W2 = (const float*)d_in[5];
  const float* b2 = (const float*)d_in[6];
  const float* WihF = (const float*)d_in[7];
  const float* WhhF = (const float*)d_in[8];
  const float* bihF = (const float*)d_in[9];
  const float* bhhF = (const float*)d_in[10];
  const float* WihB = (const float*)d_in[11];
  const float* WhhB = (const float*)d_in[12];
  const float* bihB = (const float*)d_in[13];
  const float* bhhB = (const float*)d_in[14];
  const float* Wd = (const float*)d_in[15];
  const float* bd = (const float*)d_in[16];
  float* out = (float*)d_out;

  // layout: dinv | accum | Y(67M) | C(33.5M) | A(33.5M, gx overlays A +134M)
  float* dinv  = (float*)d_ws;
  float* accum = dinv + NN_;
  float* Y     = accum + 64;
  float* C     = Y + (size_t)NN_ * 128;
  float* A     = C + (size_t)NN_ * 64;
  ushort_t* gx = (ushort_t*)A;
  // sort scratch overlays Y (dead until LSTM writes it)
  int*    srow   = (int*)Y;
  uint_t* cnt    = (uint_t*)(srow + E_);
  uint_t* start  = cnt + NN_;
  uint_t* cursor = start + NN_ + 1;
  uint_t* bsum   = cursor + NN_;

  size_t need = ((char*)A - (char*)d_ws) + 2ull * NN_ * 256 * sizeof(ushort_t);
  bool use_gx = ws_size >= need;

  // ---- degree + col-sort ----
  k_zero<<<NN_ / 256, 256, 0, stream>>>(cnt, accum);
  k_hist<<<E_ / 256, 256, 0, stream>>>(ei + E_, cnt);
  k_dinvc<<<NN_ / 256, 256, 0, stream>>>(cnt, dinv);
  k_bsum<<<512, 256, 0, stream>>>(cnt, bsum);
  k_scan512<<<1, 512, 0, stream>>>(bsum);
  k_scanadd<<<512, 256, 0, stream>>>(cnt, bsum, start, cursor);
  k_place<<<E_ / 256, 256, 0, stream>>>(ei, ei + E_, cursor, srow);

  // ---- GCN layer 1 ----
  k_gemm<FIN_, false><<<NN_ / 4, 256, 0, stream>>>(x, W1, nullptr, dinv, A);
  k_colagg<<<NN_ / 4, 256, 0, stream>>>(srow, start, dinv, A, C);

  // ---- GCN layer 2 ----
  k_gemm<64, true><<<NN_ / 4, 256, 0, stream>>>(C, W2, b1, dinv, A);
  k_colagg<<<NN_ / 4, 256, 0, stream>>>(srow, start, dinv, A, C);

  if (use_gx) {
    k_gates<<<2 * (NN_ / 64), 256, 0, stream>>>(C, b2, WihF, bihF, bhhF,
                                                WihB, bihB, bhhB, gx);
    k_lstm3<<<128, 64, 0, stream>>>(gx, WhhF, WhhB, Y);
  } else {
    k_lstm<<<128, 256, 0, stream>>>(C, b2, WihF, WhhF, bihF, bhhF,
                                    WihB, WhhB, bihB, bhhB, Y);
  }

  k_decoder<<<NN_ / 16, 256, 0, stream>>>(Y, x, mask, Wd, bd, out, accum);
  k_loss<<<1, 64, 0, stream>>>(accum, out + (size_t)NN_ * FIN_);
}

// Round 10
// 2902.874 us; speedup vs baseline: 1.7766x; 1.7336x over previous
//
#include <hip/hip_runtime.h>

#define NN_ 131072      // T*N
#define T_ 64
#define N_ 2048
#define E_ 2097152
#define FIN_ 16

typedef unsigned short ushort_t;
typedef unsigned int uint_t;

// memory-clobber LDS barrier (fallback kernel only)
#define LBAR() asm volatile("s_waitcnt lgkmcnt(0)\n\ts_barrier" ::: "memory")

__device__ __forceinline__ float bf2f(ushort_t u) {
  return __uint_as_float(((uint_t)u) << 16);
}
__device__ __forceinline__ ushort_t f2bf(float f) {
  uint_t b = __float_as_uint(f);
  b += 0x7fffu + ((b >> 16) & 1u);   // round-to-nearest-even
  return (ushort_t)(b >> 16);
}

// ---------------- zero cnt + accum ----------------
__global__ void k_zero(uint_t* __restrict__ cnt, float* __restrict__ accum) {
  int i = blockIdx.x * 256 + threadIdx.x;
  if (i < NN_) cnt[i] = 0u;
  if (i < 2) accum[i] = 0.f;
}

// ---------------- histogram of col ----------------
__global__ void k_hist(const int* __restrict__ col, uint_t* __restrict__ cnt) {
  int e = blockIdx.x * 256 + threadIdx.x;
  atomicAdd(&cnt[col[e]], 1u);
}

// ---------------- dinv from counts (+1 self loop) ----------------
__global__ void k_dinvc(const uint_t* __restrict__ cnt, float* __restrict__ dinv) {
  int v = blockIdx.x * 256 + threadIdx.x;
  dinv[v] = rsqrtf((float)cnt[v] + 1.f);
}

// ---------------- per-256-chunk sums ----------------
__global__ void k_bsum(const uint_t* __restrict__ cnt, uint_t* __restrict__ bsum) {
  int t = threadIdx.x;
  uint_t v = cnt[blockIdx.x * 256 + t];
  for (int off = 32; off; off >>= 1) v += __shfl_down(v, off);
  __shared__ uint_t s4[4];
  if ((t & 63) == 0) s4[t >> 6] = v;
  __syncthreads();
  if (t == 0) bsum[blockIdx.x] = s4[0] + s4[1] + s4[2] + s4[3];
}

// ---------------- exclusive scan of 512 chunk sums (1 block) ----------------
__global__ void k_scan512(uint_t* __restrict__ bsum) {
  __shared__ uint_t sd[512];
  int t = threadIdx.x;
  uint_t v = bsum[t];
  sd[t] = v;
  __syncthreads();
  for (int off = 1; off < 512; off <<= 1) {
    uint_t x = (t >= off) ? sd[t - off] : 0u;
    __syncthreads();
    sd[t] += x;
    __syncthreads();
  }
  bsum[t] = sd[t] - v;   // exclusive
}

// ---------------- per-chunk exclusive scan + chunk offset ----------------
__global__ void k_scanadd(const uint_t* __restrict__ cnt, const uint_t* __restrict__ bsum,
                          uint_t* __restrict__ start, uint_t* __restrict__ cursor) {
  int t = threadIdx.x;
  int i = blockIdx.x * 256 + t;
  uint_t v = cnt[i];
  __shared__ uint_t sd[256];
  sd[t] = v;
  __syncthreads();
  for (int off = 1; off < 256; off <<= 1) {
    uint_t x = (t >= off) ? sd[t - off] : 0u;
    __syncthreads();
    sd[t] += x;
    __syncthreads();
  }
  uint_t excl = sd[t] - v + bsum[blockIdx.x];
  start[i] = excl;
  cursor[i] = excl;
  if (i == NN_ - 1) start[NN_] = E_;
}

// ---------------- counting-sort placement: srow grouped by col ----------------
__global__ void k_place(const int* __restrict__ row, const int* __restrict__ col,
                        uint_t* __restrict__ cursor, int* __restrict__ srow) {
  int e = blockIdx.x * 256 + threadIdx.x;
  int c = col[e];
  uint_t pos = atomicAdd(&cursor[c], 1u);
  srow[pos] = row[e];
}

// ---------------- GEMM (NN x K) @ (K x 64), writes dinv-prescaled rows -------
template <int K, bool RELU_IN>
__global__ void k_gemm(const float* __restrict__ X, const float* __restrict__ W,
                       const float* __restrict__ bin, const float* __restrict__ dinv,
                       float* __restrict__ xws) {
  __shared__ float xs[4 * K];
  const int tid = threadIdx.x;
  const int v0 = blockIdx.x * 4;
  for (int t = tid; t < 4 * K; t += 256) {
    float v = X[(size_t)v0 * K + t];
    if (RELU_IN) v = fmaxf(v + bin[t & (K - 1)], 0.f);
    xs[t] = v;
  }
  __syncthreads();
  const int v = v0 + (tid >> 6);
  const int j = tid & 63;
  const float* xr = &xs[(tid >> 6) * K];
  float acc = 0.f;
#pragma unroll
  for (int k = 0; k < K; ++k) acc = fmaf(xr[k], W[k * 64 + j], acc);
  xws[(size_t)v * 64 + j] = dinv[v] * acc;
}

// ---------------- column-gather aggregation (no atomics) ----------------------
__global__ void k_colagg(const int* __restrict__ srow, const uint_t* __restrict__ start,
                         const float* __restrict__ dinv, const float* __restrict__ xws,
                         float* __restrict__ agg) {
  int c = blockIdx.x * 4 + (threadIdx.x >> 6);
  int lane = threadIdx.x & 63;
  uint_t s = start[c], e = start[c + 1];
  float acc = xws[(size_t)c * 64 + lane];      // self loop
  for (uint_t i = s; i < e; ++i) {
    int r = srow[i];
    acc += xws[(size_t)r * 64 + lane];
  }
  agg[(size_t)c * 64 + lane] = dinv[c] * acc;
}

// ---------------- gate-preactivation GEMM (bf16 out) --------------------------
__global__ __launch_bounds__(256) void k_gates(
    const float* __restrict__ A, const float* __restrict__ b2,
    const float* __restrict__ WihF, const float* __restrict__ bihF,
    const float* __restrict__ bhhF,
    const float* __restrict__ WihB, const float* __restrict__ bihB,
    const float* __restrict__ bhhB,
    ushort_t* __restrict__ gx) {
  const int dir = blockIdx.x >> 11;
  const int v0 = (blockIdx.x & 2047) * 64;
  const float* Wih = dir ? WihB : WihF;
  const float* bih = dir ? bihB : bihF;
  const float* bhh = dir ? bhhB : bhhF;
  const int t = threadIdx.x;

  float w[64];
#pragma unroll
  for (int k = 0; k < 64; k += 4)
    *reinterpret_cast<float4*>(&w[k]) = *reinterpret_cast<const float4*>(&Wih[t * 64 + k]);
  const float bias = bih[t] + bhh[t];

  __shared__ float xs[64 * 64];
#pragma unroll
  for (int u = 0; u < 16; ++u) {
    int idx = u * 256 + t;
    xs[idx] = fmaxf(A[(size_t)v0 * 64 + idx] + b2[idx & 63], 0.f);
  }
  __syncthreads();

  ushort_t* gp = gx + ((size_t)(dir ? NN_ : 0) + v0) * 256 + t;
  for (int r = 0; r < 64; ++r) {
    const float* xr = &xs[r * 64];
    float a0 = 0.f, a1 = 0.f, a2 = 0.f, a3 = 0.f;
#pragma unroll
    for (int k = 0; k < 64; k += 16) {
      float4 x0 = *reinterpret_cast<const float4*>(&xr[k]);
      float4 x1 = *reinterpret_cast<const float4*>(&xr[k + 4]);
      float4 x2 = *reinterpret_cast<const float4*>(&xr[k + 8]);
      float4 x3 = *reinterpret_cast<const float4*>(&xr[k + 12]);
      a0 = fmaf(x0.x, w[k+0], a0);  a0 = fmaf(x0.y, w[k+1], a0);
      a0 = fmaf(x0.z, w[k+2], a0);  a0 = fmaf(x0.w, w[k+3], a0);
      a1 = fmaf(x1.x, w[k+4], a1);  a1 = fmaf(x1.y, w[k+5], a1);
      a1 = fmaf(x1.z, w[k+6], a1);  a1 = fmaf(x1.w, w[k+7], a1);
      a2 = fmaf(x2.x, w[k+8], a2);  a2 = fmaf(x2.y, w[k+9], a2);
      a2 = fmaf(x2.z, w[k+10], a2); a2 = fmaf(x2.w, w[k+11], a2);
      a3 = fmaf(x3.x, w[k+12], a3); a3 = fmaf(x3.y, w[k+13], a3);
      a3 = fmaf(x3.z, w[k+14], a3); a3 = fmaf(x3.w, w[k+15], a3);
    }
    gp[(size_t)r * 256] = f2bf(bias + (a0 + a1) + (a2 + a3));
  }
}

// ---------------- persistent LSTM: one wave/stream, f16 weights in registers --
// Lane l owns hidden unit l (4 gate rows in 128 f16-pair VGPRs). h kept in LDS
// as f16 (128 B): own-lane ds_write_b16, 8 broadcast uint4 reads per step.
// Register budget kept < 256 to avoid AGPR demotion (round-7 failure mode).
#if __has_builtin(__builtin_amdgcn_fdot2)
#define HAVE_DOT2 1
typedef __fp16 half2v __attribute__((ext_vector_type(2)));
__device__ __forceinline__ half2v u2h(uint_t u) { union { uint_t u; half2v h; } x; x.u = u; return x.h; }
#else
#define HAVE_DOT2 0
#endif

#define GRP_ 4   // steps per prefetch group

__global__ __launch_bounds__(64, 1) void k_lstm3(
    const ushort_t* __restrict__ gx,
    const float* __restrict__ WhhF, const float* __restrict__ WhhB,
    float* __restrict__ y) {
  const int b   = blockIdx.x & 63;
  const int dir = blockIdx.x >> 6;
  const int l   = threadIdx.x;
  const float* Whh = dir ? WhhB : WhhF;

#if HAVE_DOT2
  half2v wp[128];   // wp[g4*32 + m] = (Whh[g4*64+l][2m], Whh[g4*64+l][2m+1]) f16
#pragma unroll
  for (int g4 = 0; g4 < 4; ++g4) {
#pragma unroll
    for (int k4 = 0; k4 < 16; ++k4) {
      float4 f4 = *reinterpret_cast<const float4*>(&Whh[(size_t)(g4 * 64 + l) * 64 + 4 * k4]);
      wp[g4 * 32 + 2 * k4]     = __builtin_amdgcn_cvt_pkrtz(f4.x, f4.y);
      wp[g4 * 32 + 2 * k4 + 1] = __builtin_amdgcn_cvt_pkrtz(f4.z, f4.w);
    }
  }
  __shared__ __align__(16) __fp16 hsh[64];   // h state, f16, 128 B
  hsh[l] = (__fp16)0.f;                      // same-wave in-order DS
  float c = 0.f;

  const long stride = dir ? -256 : 256;
  const long ystr   = dir ? -128 : 128;
  const int s0 = dir ? N_ - 1 : 0;
  const ushort_t* p = gx + ((size_t)dir * NN_ + (size_t)b * N_ + s0) * 256 + l;
  float* yp = y + ((size_t)b * N_ + s0) * 128 + (size_t)dir * 64 + l;

  ushort_t zc[GRP_][4], zn[GRP_][4];         // raw bf16 bits (low reg footprint)
#pragma unroll
  for (int i = 0; i < GRP_; ++i)
#pragma unroll
    for (int g4 = 0; g4 < 4; ++g4)
      zc[i][g4] = p[i * stride + g4 * 64];
  p += GRP_ * stride;

  const uint4* hsq = reinterpret_cast<const uint4*>(hsh);

  for (int g = 0; g < N_ / GRP_; ++g) {
    if (g != N_ / GRP_ - 1) {
#pragma unroll
      for (int i = 0; i < GRP_; ++i)
#pragma unroll
        for (int g4 = 0; g4 < 4; ++g4)
          zn[i][g4] = p[i * stride + g4 * 64];
    }
    p += GRP_ * stride;

    float yv[GRP_];
#pragma unroll
    for (int i = 0; i < GRP_; ++i) {
      // h pairs: 8 broadcast b128 reads (conflict-free), all issued up front
      uint_t hu[32];
#pragma unroll
      for (int q = 0; q < 8; ++q) {
        uint4 hq = hsq[q];
        hu[4*q+0] = hq.x; hu[4*q+1] = hq.y; hu[4*q+2] = hq.z; hu[4*q+3] = hq.w;
      }
      float a0 = bf2f(zc[i][0]), a1 = bf2f(zc[i][1]);
      float a2 = bf2f(zc[i][2]), a3 = bf2f(zc[i][3]);
#pragma unroll
      for (int m = 0; m < 32; ++m) {
        half2v hm = u2h(hu[m]);
        a0 = __builtin_amdgcn_fdot2(wp[m],      hm, a0, false);
        a1 = __builtin_amdgcn_fdot2(wp[32 + m], hm, a1, false);
        a2 = __builtin_amdgcn_fdot2(wp[64 + m], hm, a2, false);
        a3 = __builtin_amdgcn_fdot2(wp[96 + m], hm, a3, false);
      }
      float si_ = __fdividef(1.f, 1.f + __expf(-a0));
      float sf  = __fdividef(1.f, 1.f + __expf(-a1));
      float tg  = 1.f - __fdividef(2.f, __expf(2.f * a2) + 1.f);
      float so  = __fdividef(1.f, 1.f + __expf(-a3));
      c = sf * c + si_ * tg;
      float tc = 1.f - __fdividef(2.f, __expf(2.f * c) + 1.f);
      float hh = so * tc;
      hsh[l] = (__fp16)hh;     // ds_write_b16; next step's reads see it (in-order)
      yv[i] = hh;
    }
#pragma unroll
    for (int i = 0; i < GRP_; ++i) yp[(long)i * ystr] = yv[i];
    yp += GRP_ * ystr;
#pragma unroll
    for (int i = 0; i < GRP_; ++i)
#pragma unroll
      for (int g4 = 0; g4 < 4; ++g4) zc[i][g4] = zn[i][g4];
  }
#else
  // f32 fallback (no dot2): register weights
  float wf[256];
#pragma unroll
  for (int i = 0; i < 64; ++i) {
    const int g4 = i >> 4, k4 = i & 15;
    float4 f4 = *reinterpret_cast<const float4*>(&Whh[(size_t)(g4 * 64 + l) * 64 + 4 * k4]);
    wf[g4 * 64 + 4 * k4 + 0] = f4.x; wf[g4 * 64 + 4 * k4 + 1] = f4.y;
    wf[g4 * 64 + 4 * k4 + 2] = f4.z; wf[g4 * 64 + 4 * k4 + 3] = f4.w;
  }
  __shared__ __align__(16) float hs[64];
  hs[l] = 0.f;
  float c = 0.f;
  const long stride = dir ? -256 : 256;
  const long ystr   = dir ? -128 : 128;
  const int s0 = dir ? N_ - 1 : 0;
  const ushort_t* p = gx + ((size_t)dir * NN_ + (size_t)b * N_ + s0) * 256 + l;
  float* yp = y + ((size_t)b * N_ + s0) * 128 + (size_t)dir * 64 + l;
  for (int s = 0; s < N_; ++s) {
    float acc[4];
#pragma unroll
    for (int g4 = 0; g4 < 4; ++g4) acc[g4] = bf2f(p[g4 * 64]);
    p += stride;
#pragma unroll
    for (int k4 = 0; k4 < 16; ++k4) {
      float4 hv = *reinterpret_cast<const float4*>(&hs[4 * k4]);
#pragma unroll
      for (int g4 = 0; g4 < 4; ++g4) {
        acc[g4] = fmaf(hv.x, wf[g4*64+4*k4+0], acc[g4]);
        acc[g4] = fmaf(hv.y, wf[g4*64+4*k4+1], acc[g4]);
        acc[g4] = fmaf(hv.z, wf[g4*64+4*k4+2], acc[g4]);
        acc[g4] = fmaf(hv.w, wf[g4*64+4*k4+3], acc[g4]);
      }
    }
    float si_ = __fdividef(1.f, 1.f + __expf(-acc[0]));
    float sf  = __fdividef(1.f, 1.f + __expf(-acc[1]));
    float tg  = 1.f - __fdividef(2.f, __expf(2.f * acc[2]) + 1.f);
    float so  = __fdividef(1.f, 1.f + __expf(-acc[3]));
    c = sf * c + si_ * tg;
    float tc = 1.f - __fdividef(2.f, __expf(2.f * c) + 1.f);
    float hh = so * tc;
    hs[l] = hh;
    *yp = hh;
    yp += ystr;
  }
#endif
}

// ---------------- fallback persistent LSTM (round-3 version, safe path) -------
__global__ __launch_bounds__(256) void k_lstm(
    const float* __restrict__ h2raw, const float* __restrict__ b2,
    const float* __restrict__ WihF, const float* __restrict__ WhhF,
    const float* __restrict__ bihF, const float* __restrict__ bhhF,
    const float* __restrict__ WihB, const float* __restrict__ WhhB,
    const float* __restrict__ bihB, const float* __restrict__ bhhB,
    float* __restrict__ y) {
  const int b   = blockIdx.x & 63;
  const int dir = blockIdx.x >> 6;
  const float* Wih = dir ? WihB : WihF;
  const float* Whh = dir ? WhhB : WhhF;
  const float* bih = dir ? bihB : bihF;
  const float* bhh = dir ? bhhB : bhhF;
  const int j = threadIdx.x;

  float wih[64], whh[64];
#pragma unroll
  for (int k = 0; k < 64; k += 4) {
    *reinterpret_cast<float4*>(&wih[k]) = *reinterpret_cast<const float4*>(&Wih[j * 64 + k]);
    *reinterpret_cast<float4*>(&whh[k]) = *reinterpret_cast<const float4*>(&Whh[j * 64 + k]);
  }
  const float bias = bih[j] + bhh[j];
  const float b2j = (j < 64) ? b2[j] : 0.f;

  __shared__ __align__(16) float xbuf[64];
  __shared__ __align__(16) float hbuf[64];
  __shared__ float gbuf[256];
  float c = 0.f;
  if (j < 64) hbuf[j] = 0.f;

  float xc = 0.f, xn = 0.f;
  if (j < 64) {
    const int s0 = dir ? N_ - 1 : 0;
    const int s1 = dir ? N_ - 2 : 1;
    xc = h2raw[((size_t)b * N_ + s0) * 64 + j];
    xn = h2raw[((size_t)b * N_ + s1) * 64 + j];
  }

  for (int si = 0; si < N_; ++si) {
    const int s = dir ? (N_ - 1 - si) : si;
    const size_t vrow = (size_t)b * N_ + s;
    if (j < 64) xbuf[j] = fmaxf(xc + b2j, 0.f);
    LBAR();

    float xp = 0.f;
    {
      int si2 = si + 2; if (si2 >= N_) si2 = N_ - 1;
      const int s2 = dir ? (N_ - 1 - si2) : si2;
      if (j < 64) xp = h2raw[((size_t)b * N_ + s2) * 64 + j];
    }

    float a0 = 0.f, a1 = 0.f, a2 = 0.f, a3 = 0.f;
#pragma unroll
    for (int k = 0; k < 64; k += 16) {
      float4 xv0 = *reinterpret_cast<const float4*>(&xbuf[k]);
      float4 hv0 = *reinterpret_cast<const float4*>(&hbuf[k]);
      a0 = fmaf(xv0.x, wih[k+0], a0); a0 = fmaf(hv0.x, whh[k+0], a0);
      a0 = fmaf(xv0.y, wih[k+1], a0); a0 = fmaf(hv0.y, whh[k+1], a0);
      a0 = fmaf(xv0.z, wih[k+2], a0); a0 = fmaf(hv0.z, whh[k+2], a0);
      a0 = fmaf(xv0.w, wih[k+3], a0); a0 = fmaf(hv0.w, whh[k+3], a0);
      float4 xv1 = *reinterpret_cast<const float4*>(&xbuf[k+4]);
      float4 hv1 = *reinterpret_cast<const float4*>(&hbuf[k+4]);
      a1 = fmaf(xv1.x, wih[k+4], a1); a1 = fmaf(hv1.x, whh[k+4], a1);
      a1 = fmaf(xv1.y, wih[k+5], a1); a1 = fmaf(hv1.y, whh[k+5], a1);
      a1 = fmaf(xv1.z, wih[k+6], a1); a1 = fmaf(hv1.z, whh[k+6], a1);
      a1 = fmaf(xv1.w, wih[k+7], a1); a1 = fmaf(hv1.w, whh[k+7], a1);
      float4 xv2 = *reinterpret_cast<const float4*>(&xbuf[k+8]);
      float4 hv2 = *reinterpret_cast<const float4*>(&hbuf[k+8]);
      a2 = fmaf(xv2.x, wih[k+8], a2); a2 = fmaf(hv2.x, whh[k+8], a2);
      a2 = fmaf(xv2.y, wih[k+9], a2); a2 = fmaf(hv2.y, whh[k+9], a2);
      a2 = fmaf(xv2.z, wih[k+10], a2); a2 = fmaf(hv2.z, whh[k+10], a2);
      a2 = fmaf(xv2.w, wih[k+11], a2); a2 = fmaf(hv2.w, whh[k+11], a2);
      float4 xv3 = *reinterpret_cast<const float4*>(&xbuf[k+12]);
      float4 hv3 = *reinterpret_cast<const float4*>(&hbuf[k+12]);
      a3 = fmaf(xv3.x, wih[k+12], a3); a3 = fmaf(hv3.x, whh[k+12], a3);
      a3 = fmaf(xv3.y, wih[k+13], a3); a3 = fmaf(hv3.y, whh[k+13], a3);
      a3 = fmaf(xv3.z, wih[k+14], a3); a3 = fmaf(hv3.z, whh[k+14], a3);
      a3 = fmaf(xv3.w, wih[k+15], a3); a3 = fmaf(hv3.w, whh[k+15], a3);
    }
    gbuf[j] = bias + (a0 + a1) + (a2 + a3);
    LBAR();

    if (j < 64) {
      float gi = gbuf[j], gf = gbuf[64 + j], gg = gbuf[128 + j], go = gbuf[192 + j];
      float si_ = __fdividef(1.f, 1.f + __expf(-gi));
      float sf  = __fdividef(1.f, 1.f + __expf(-gf));
      float so  = __fdividef(1.f, 1.f + __expf(-go));
      float tg  = 1.f - __fdividef(2.f, __expf(2.f * gg) + 1.f);
      c = sf * c + si_ * tg;
      float tc = 1.f - __fdividef(2.f, __expf(2.f * c) + 1.f);
      float hh = so * tc;
      hbuf[j] = hh;
      y[vrow * 128 + (size_t)dir * 64 + j] = hh;
    }
    xc = xn; xn = xp;
  }
}

// ---------------- decoder + masked MSE (LDS-staged y rows) ----------------
__global__ __launch_bounds__(256) void k_decoder(
    const float* __restrict__ y, const float* __restrict__ x,
    const float* __restrict__ mask, const float* __restrict__ Wd,
    const float* __restrict__ bd, float* __restrict__ out,
    float* __restrict__ accum) {
  __shared__ float ys[16 * 132];           // 16 rows, padded to 132 floats
  const int tid = threadIdx.x;
  const size_t base = (size_t)blockIdx.x * 2048;
#pragma unroll
  for (int u = 0; u < 2; ++u) {
    int idx = u * 1024 + tid * 4;
    *reinterpret_cast<float4*>(&ys[(idx >> 7) * 132 + (idx & 127)]) =
        *reinterpret_cast<const float4*>(&y[base + idx]);
  }
  __syncthreads();
  size_t v = (size_t)blockIdx.x * 16 + (tid >> 4);
  int f = tid & 15;
  const float* yr = &ys[(tid >> 4) * 132];
  float acc = bd[f];
#pragma unroll
  for (int jj = 0; jj < 128; jj += 4) {
    float4 yv = *reinterpret_cast<const float4*>(&yr[jj]);
    float4 wv = *reinterpret_cast<const float4*>(&Wd[f * 128 + jj]);
    acc = fmaf(yv.x, wv.x, acc); acc = fmaf(yv.y, wv.y, acc);
    acc = fmaf(yv.z, wv.z, acc); acc = fmaf(yv.w, wv.w, acc);
  }
  size_t o = v * 16 + f;
  float xv = x[o], m = mask[o];
  float d = acc - xv;
  out[o] = (m != 0.f) ? xv : acc;
  float num = m * d * d;
  float den = m;
#pragma unroll
  for (int off = 32; off > 0; off >>= 1) {
    num += __shfl_down(num, off);
    den += __shfl_down(den, off);
  }
  if ((tid & 63) == 0) {
    unsafeAtomicAdd(&accum[0], num);
    unsafeAtomicAdd(&accum[1], den);
  }
}

__global__ void k_loss(const float* __restrict__ accum, float* __restrict__ out_loss) {
  if (threadIdx.x == 0) out_loss[0] = accum[0] / (accum[1] + 1e-8f);
}

// ---------------- launch ----------------
extern "C" void kernel_launch(void* const* d_in, const int* in_sizes, int n_in,
                              void* d_out, int out_size, void* d_ws, size_t ws_size,
                              hipStream_t stream) {
  const float* x    = (const float*)d_in[0];
  const int*   ei   = (const int*)d_in[1];   // row = ei, col = ei + E_
  const float* mask = (const float*)d_in[2];
  const float* W1 = (const float*)d_in[3];
  const float* b1 = (const float*)d_in[4];
  const float* W2 = (const float*)d_in[5];
  const float* b2 = (const float*)d_in[6];
  const float* WihF = (const float*)d_in[7];
  const float* WhhF = (const float*)d_in[8];
  const float* bihF = (const float*)d_in[9];
  const float* bhhF = (const float*)d_in[10];
  const float* WihB = (const float*)d_in[11];
  const float* WhhB = (const float*)d_in[12];
  const float* bihB = (const float*)d_in[13];
  const float* bhhB = (const float*)d_in[14];
  const float* Wd = (const float*)d_in[15];
  const float* bd = (const float*)d_in[16];
  float* out = (float*)d_out;

  // layout: dinv | accum | Y(67M) | C(33.5M) | A(33.5M, gx overlays A +134M)
  float* dinv  = (float*)d_ws;
  float* accum = dinv + NN_;
  float* Y     = accum + 64;
  float* C     = Y + (size_t)NN_ * 128;
  float* A     = C + (size_t)NN_ * 64;
  ushort_t* gx = (ushort_t*)A;
  // sort scratch overlays Y (dead until LSTM writes it)
  int*    srow   = (int*)Y;
  uint_t* cnt    = (uint_t*)(srow + E_);
  uint_t* start  = cnt + NN_;
  uint_t* cursor = start + NN_ + 1;
  uint_t* bsum   = cursor + NN_;

  size_t need = ((char*)A - (char*)d_ws) + 2ull * NN_ * 256 * sizeof(ushort_t);
  bool use_gx = ws_size >= need;

  // ---- degree + col-sort ----
  k_zero<<<NN_ / 256, 256, 0, stream>>>(cnt, accum);
  k_hist<<<E_ / 256, 256, 0, stream>>>(ei + E_, cnt);
  k_dinvc<<<NN_ / 256, 256, 0, stream>>>(cnt, dinv);
  k_bsum<<<512, 256, 0, stream>>>(cnt, bsum);
  k_scan512<<<1, 512, 0, stream>>>(bsum);
  k_scanadd<<<512, 256, 0, stream>>>(cnt, bsum, start, cursor);
  k_place<<<E_ / 256, 256, 0, stream>>>(ei, ei + E_, cursor, srow);

  // ---- GCN layer 1 ----
  k_gemm<FIN_, false><<<NN_ / 4, 256, 0, stream>>>(x, W1, nullptr, dinv, A);
  k_colagg<<<NN_ / 4, 256, 0, stream>>>(srow, start, dinv, A, C);

  // ---- GCN layer 2 ----
  k_gemm<64, true><<<NN_ / 4, 256, 0, stream>>>(C, W2, b1, dinv, A);
  k_colagg<<<NN_ / 4, 256, 0, stream>>>(srow, start, dinv, A, C);

  if (use_gx) {
    k_gates<<<2 * (NN_ / 64), 256, 0, stream>>>(C, b2, WihF, bihF, bhhF,
                                                WihB, bihB, bhhB, gx);
    k_lstm3<<<128, 64, 0, stream>>>(gx, WhhF, WhhB, Y);
  } else {
    k_lstm<<<128, 256, 0, stream>>>(C, b2, WihF, WhhF, bihF, bhhF,
                                    WihB, WhhB, bihB, bhhB, Y);
  }

  k_decoder<<<NN_ / 16, 256, 0, stream>>>(Y, x, mask, Wd, bd, out, accum);
  k_loss<<<1, 64, 0, stream>>>(accum, out + (size_t)NN_ * FIN_);
}

// Round 11
// 2381.684 us; speedup vs baseline: 2.1654x; 1.2188x over previous
//
#include <hip/hip_runtime.h>

#define NN_ 131072      // T*N
#define T_ 64
#define N_ 2048
#define E_ 2097152
#define FIN_ 16

typedef unsigned short ushort_t;
typedef unsigned int uint_t;

// memory-clobber LDS barrier (fallback kernel only)
#define LBAR() asm volatile("s_waitcnt lgkmcnt(0)\n\ts_barrier" ::: "memory")

// Clobber-free LDS barrier (lstm2-proven): no vmcnt drain; sched_barrier pins
// DS ops in-phase (rule #18).
__device__ __forceinline__ void lbar2() {
  __builtin_amdgcn_sched_barrier(0);
  asm volatile("s_waitcnt lgkmcnt(0)");
  __builtin_amdgcn_s_barrier();
  __builtin_amdgcn_sched_barrier(0);
}

__device__ __forceinline__ float bf2f(ushort_t u) {
  return __uint_as_float(((uint_t)u) << 16);
}
__device__ __forceinline__ ushort_t f2bf(float f) {
  uint_t b = __float_as_uint(f);
  b += 0x7fffu + ((b >> 16) & 1u);   // round-to-nearest-even
  return (ushort_t)(b >> 16);
}

#if __has_builtin(__builtin_amdgcn_fdot2)
#define HAVE_DOT2 1
typedef __fp16 half2v __attribute__((ext_vector_type(2)));
__device__ __forceinline__ half2v u2h(uint_t u) { union { uint_t u; half2v h; } x; x.u = u; return x.h; }
__device__ __forceinline__ uint_t h2u(half2v h) { union { uint_t u; half2v h; } x; x.h = h; return x.u; }
#else
#define HAVE_DOT2 0
#endif

// ---------------- zero cnt + accum ----------------
__global__ void k_zero(uint_t* __restrict__ cnt, float* __restrict__ accum) {
  int i = blockIdx.x * 256 + threadIdx.x;
  if (i < NN_) cnt[i] = 0u;
  if (i < 2) accum[i] = 0.f;
}

// ---------------- histogram of col ----------------
__global__ void k_hist(const int* __restrict__ col, uint_t* __restrict__ cnt) {
  int e = blockIdx.x * 256 + threadIdx.x;
  atomicAdd(&cnt[col[e]], 1u);
}

// ---------------- dinv from counts (+1 self loop) ----------------
__global__ void k_dinvc(const uint_t* __restrict__ cnt, float* __restrict__ dinv) {
  int v = blockIdx.x * 256 + threadIdx.x;
  dinv[v] = rsqrtf((float)cnt[v] + 1.f);
}

// ---------------- per-256-chunk sums ----------------
__global__ void k_bsum(const uint_t* __restrict__ cnt, uint_t* __restrict__ bsum) {
  int t = threadIdx.x;
  uint_t v = cnt[blockIdx.x * 256 + t];
  for (int off = 32; off; off >>= 1) v += __shfl_down(v, off);
  __shared__ uint_t s4[4];
  if ((t & 63) == 0) s4[t >> 6] = v;
  __syncthreads();
  if (t == 0) bsum[blockIdx.x] = s4[0] + s4[1] + s4[2] + s4[3];
}

// ---------------- exclusive scan of 512 chunk sums (1 block) ----------------
__global__ void k_scan512(uint_t* __restrict__ bsum) {
  __shared__ uint_t sd[512];
  int t = threadIdx.x;
  uint_t v = bsum[t];
  sd[t] = v;
  __syncthreads();
  for (int off = 1; off < 512; off <<= 1) {
    uint_t x = (t >= off) ? sd[t - off] : 0u;
    __syncthreads();
    sd[t] += x;
    __syncthreads();
  }
  bsum[t] = sd[t] - v;   // exclusive
}

// ---------------- per-chunk exclusive scan + chunk offset ----------------
__global__ void k_scanadd(const uint_t* __restrict__ cnt, const uint_t* __restrict__ bsum,
                          uint_t* __restrict__ start, uint_t* __restrict__ cursor) {
  int t = threadIdx.x;
  int i = blockIdx.x * 256 + t;
  uint_t v = cnt[i];
  __shared__ uint_t sd[256];
  sd[t] = v;
  __syncthreads();
  for (int off = 1; off < 256; off <<= 1) {
    uint_t x = (t >= off) ? sd[t - off] : 0u;
    __syncthreads();
    sd[t] += x;
    __syncthreads();
  }
  uint_t excl = sd[t] - v + bsum[blockIdx.x];
  start[i] = excl;
  cursor[i] = excl;
  if (i == NN_ - 1) start[NN_] = E_;
}

// ---------------- counting-sort placement: srow grouped by col ----------------
__global__ void k_place(const int* __restrict__ row, const int* __restrict__ col,
                        uint_t* __restrict__ cursor, int* __restrict__ srow) {
  int e = blockIdx.x * 256 + threadIdx.x;
  int c = col[e];
  uint_t pos = atomicAdd(&cursor[c], 1u);
  srow[pos] = row[e];
}

// ---------------- GEMM (NN x K) @ (K x 64), writes dinv-prescaled rows -------
template <int K, bool RELU_IN>
__global__ void k_gemm(const float* __restrict__ X, const float* __restrict__ W,
                       const float* __restrict__ bin, const float* __restrict__ dinv,
                       float* __restrict__ xws) {
  __shared__ float xs[4 * K];
  const int tid = threadIdx.x;
  const int v0 = blockIdx.x * 4;
  for (int t = tid; t < 4 * K; t += 256) {
    float v = X[(size_t)v0 * K + t];
    if (RELU_IN) v = fmaxf(v + bin[t & (K - 1)], 0.f);
    xs[t] = v;
  }
  __syncthreads();
  const int v = v0 + (tid >> 6);
  const int j = tid & 63;
  const float* xr = &xs[(tid >> 6) * K];
  float acc = 0.f;
#pragma unroll
  for (int k = 0; k < K; ++k) acc = fmaf(xr[k], W[k * 64 + j], acc);
  xws[(size_t)v * 64 + j] = dinv[v] * acc;
}

// ---------------- column-gather aggregation (no atomics, 4-way ILP) -----------
__global__ void k_colagg(const int* __restrict__ srow, const uint_t* __restrict__ start,
                         const float* __restrict__ dinv, const float* __restrict__ xws,
                         float* __restrict__ agg) {
  int c = blockIdx.x * 4 + (threadIdx.x >> 6);
  int lane = threadIdx.x & 63;
  uint_t s = start[c], e = start[c + 1];
  float a0 = xws[(size_t)c * 64 + lane];   // self loop
  float a1 = 0.f, a2 = 0.f, a3 = 0.f;
  uint_t i = s;
  for (; i + 4 <= e; i += 4) {
    int r0 = srow[i], r1 = srow[i + 1], r2 = srow[i + 2], r3 = srow[i + 3];
    a0 += xws[(size_t)r0 * 64 + lane];
    a1 += xws[(size_t)r1 * 64 + lane];
    a2 += xws[(size_t)r2 * 64 + lane];
    a3 += xws[(size_t)r3 * 64 + lane];
  }
  for (; i < e; ++i) a0 += xws[(size_t)srow[i] * 64 + lane];
  agg[(size_t)c * 64 + lane] = dinv[c] * ((a0 + a1) + (a2 + a3));
}

// ---------------- gate-preactivation GEMM (f16 dot2, bf16 out) ----------------
__global__ __launch_bounds__(256) void k_gates(
    const float* __restrict__ A, const float* __restrict__ b2,
    const float* __restrict__ WihF, const float* __restrict__ bihF,
    const float* __restrict__ bhhF,
    const float* __restrict__ WihB, const float* __restrict__ bihB,
    const float* __restrict__ bhhB,
    ushort_t* __restrict__ gx) {
  const int dir = blockIdx.x >> 11;
  const int v0 = (blockIdx.x & 2047) * 64;
  const float* Wih = dir ? WihB : WihF;
  const float* bih = dir ? bihB : bihF;
  const float* bhh = dir ? bhhB : bhhF;
  const int t = threadIdx.x;
  const float bias = bih[t] + bhh[t];

#if HAVE_DOT2
  half2v wp[32];
#pragma unroll
  for (int k4 = 0; k4 < 16; ++k4) {
    float4 f4 = *reinterpret_cast<const float4*>(&Wih[(size_t)t * 64 + 4 * k4]);
    wp[2 * k4]     = __builtin_amdgcn_cvt_pkrtz(f4.x, f4.y);
    wp[2 * k4 + 1] = __builtin_amdgcn_cvt_pkrtz(f4.z, f4.w);
  }
  __shared__ __align__(16) uint_t xs2[64 * 32];   // f16-pair rows, 8 KB
  const float2* A2 = reinterpret_cast<const float2*>(A + (size_t)v0 * 64);
#pragma unroll
  for (int u = 0; u < 8; ++u) {
    int pi = u * 256 + t;
    float2 f = A2[pi];
    int d0 = (2 * pi) & 63;
    float q0 = fmaxf(f.x + b2[d0], 0.f);
    float q1 = fmaxf(f.y + b2[d0 + 1], 0.f);
    xs2[pi] = h2u(__builtin_amdgcn_cvt_pkrtz(q0, q1));
  }
  __syncthreads();
  const uint4* xq = reinterpret_cast<const uint4*>(xs2);
  ushort_t* gp = gx + ((size_t)(dir ? NN_ : 0) + v0) * 256 + t;
  for (int r = 0; r < 64; ++r) {
    float a = bias;
#pragma unroll
    for (int q = 0; q < 8; ++q) {
      uint4 x4 = xq[r * 8 + q];
      a = __builtin_amdgcn_fdot2(wp[4 * q],     u2h(x4.x), a, false);
      a = __builtin_amdgcn_fdot2(wp[4 * q + 1], u2h(x4.y), a, false);
      a = __builtin_amdgcn_fdot2(wp[4 * q + 2], u2h(x4.z), a, false);
      a = __builtin_amdgcn_fdot2(wp[4 * q + 3], u2h(x4.w), a, false);
    }
    gp[(size_t)r * 256] = f2bf(a);
  }
#else
  float w[64];
#pragma unroll
  for (int k = 0; k < 64; k += 4)
    *reinterpret_cast<float4*>(&w[k]) = *reinterpret_cast<const float4*>(&Wih[t * 64 + k]);
  __shared__ float xs[64 * 64];
#pragma unroll
  for (int u = 0; u < 16; ++u) {
    int idx = u * 256 + t;
    xs[idx] = fmaxf(A[(size_t)v0 * 64 + idx] + b2[idx & 63], 0.f);
  }
  __syncthreads();
  ushort_t* gp = gx + ((size_t)(dir ? NN_ : 0) + v0) * 256 + t;
  for (int r = 0; r < 64; ++r) {
    const float* xr = &xs[r * 64];
    float a = bias;
#pragma unroll
    for (int k = 0; k < 64; ++k) a = fmaf(xr[k], w[k], a);
    gp[(size_t)r * 256] = f2bf(a);
  }
#endif
}

// ---------------- persistent LSTM: 2 waves/stream (gate-pair split) -----------
// 128 blocks x 128 threads. Wave 0 computes gates i,f; wave 1 computes g,o and
// owns c/h. Each wave holds only 64 weight VGPRs (no AGPR demotion). Cross-wave
// via sbuf (sigma_i, sigma_f) at barrier A; h (f16) published at barrier B.
#define GRP_ 4

__global__ __launch_bounds__(128, 1) void k_lstm4(
    const ushort_t* __restrict__ gx,
    const float* __restrict__ WhhF, const float* __restrict__ WhhB,
    float* __restrict__ y) {
  const int b   = blockIdx.x & 63;
  const int dir = blockIdx.x >> 6;
  const int l   = threadIdx.x & 63;
  const int w   = threadIdx.x >> 6;      // wave id: 0 -> {i,f}, 1 -> {g,o}
  const float* Whh = dir ? WhhB : WhhF;

#if HAVE_DOT2
  half2v wp[64];
#pragma unroll
  for (int jg = 0; jg < 2; ++jg) {
    const size_t grow = (size_t)((2 * w + jg) * 64 + l) * 64;
#pragma unroll
    for (int k4 = 0; k4 < 16; ++k4) {
      float4 f4 = *reinterpret_cast<const float4*>(&Whh[grow + 4 * k4]);
      wp[jg * 32 + 2 * k4]     = __builtin_amdgcn_cvt_pkrtz(f4.x, f4.y);
      wp[jg * 32 + 2 * k4 + 1] = __builtin_amdgcn_cvt_pkrtz(f4.z, f4.w);
    }
  }
  __shared__ __align__(16) __fp16 hsh[64];
  __shared__ float sbuf[2][64];
  if (w == 1) hsh[l] = (__fp16)0.f;
  float c = 0.f;
  lbar2();                                  // publish hsh init

  const long stride = dir ? -256 : 256;
  const long ystr   = dir ? -128 : 128;
  const int s0 = dir ? N_ - 1 : 0;
  const ushort_t* p = gx + ((size_t)dir * NN_ + (size_t)b * N_ + s0) * 256 + 2 * w * 64 + l;
  float* yp = y + ((size_t)b * N_ + s0) * 128 + (size_t)dir * 64 + l;

  ushort_t zc[GRP_][2], zn[GRP_][2];
#pragma unroll
  for (int i = 0; i < GRP_; ++i) {
    zc[i][0] = p[i * stride];
    zc[i][1] = p[i * stride + 64];
  }
  p += GRP_ * stride;

  const uint4* hsq = reinterpret_cast<const uint4*>(hsh);

  for (int g = 0; g < N_ / GRP_; ++g) {
    if (g != N_ / GRP_ - 1) {
#pragma unroll
      for (int i = 0; i < GRP_; ++i) {
        zn[i][0] = p[i * stride];
        zn[i][1] = p[i * stride + 64];
      }
    }
    p += GRP_ * stride;

    float yv[GRP_];
#pragma unroll
    for (int i = 0; i < GRP_; ++i) {
      uint_t hu[32];
#pragma unroll
      for (int q = 0; q < 8; ++q) {         // 8 broadcast b128 reads of h
        uint4 hq = hsq[q];
        hu[4*q] = hq.x; hu[4*q+1] = hq.y; hu[4*q+2] = hq.z; hu[4*q+3] = hq.w;
      }
      float a0 = bf2f(zc[i][0]), a1 = bf2f(zc[i][1]);
#pragma unroll
      for (int m = 0; m < 32; ++m) {        // 64 fdot2 per wave (parallel SIMDs)
        half2v hm = u2h(hu[m]);
        a0 = __builtin_amdgcn_fdot2(wp[m],      hm, a0, false);
        a1 = __builtin_amdgcn_fdot2(wp[32 + m], hm, a1, false);
      }
      float tg = 0.f, so = 0.f;
      if (w == 0) {
        sbuf[0][l] = __fdividef(1.f, 1.f + __expf(-a0));   // sigma(i)
        sbuf[1][l] = __fdividef(1.f, 1.f + __expf(-a1));   // sigma(f)
      } else {
        tg = 1.f - __fdividef(2.f, __expf(2.f * a0) + 1.f); // tanh(g)
        so = __fdividef(1.f, 1.f + __expf(-a1));            // sigma(o)
      }
      lbar2();                              // A: sbuf published; h reads done
      if (w == 1) {
        float si_ = sbuf[0][l], sf = sbuf[1][l];
        c = sf * c + si_ * tg;
        float tc = 1.f - __fdividef(2.f, __expf(2.f * c) + 1.f);
        float hh = so * tc;
        hsh[l] = (__fp16)hh;
        yv[i] = hh;
      }
      lbar2();                              // B: h(t) published
    }
    if (w == 1) {
#pragma unroll
      for (int i = 0; i < GRP_; ++i) yp[(long)i * ystr] = yv[i];
    }
    yp += GRP_ * ystr;
#pragma unroll
    for (int i = 0; i < GRP_; ++i) { zc[i][0] = zn[i][0]; zc[i][1] = zn[i][1]; }
  }
#else
  // f32 fallback: wave 1 runs the whole recurrence alone (no barriers)
  if (w == 1) {
    float wf[256];
#pragma unroll
    for (int i = 0; i < 64; ++i) {
      const int g4 = i >> 4, k4 = i & 15;
      float4 f4 = *reinterpret_cast<const float4*>(&Whh[(size_t)(g4 * 64 + l) * 64 + 4 * k4]);
      wf[g4 * 64 + 4 * k4 + 0] = f4.x; wf[g4 * 64 + 4 * k4 + 1] = f4.y;
      wf[g4 * 64 + 4 * k4 + 2] = f4.z; wf[g4 * 64 + 4 * k4 + 3] = f4.w;
    }
    __shared__ __align__(16) float hs[64];
    hs[l] = 0.f;
    float c = 0.f;
    const long stride = dir ? -256 : 256;
    const long ystr   = dir ? -128 : 128;
    const int s0 = dir ? N_ - 1 : 0;
    const ushort_t* p = gx + ((size_t)dir * NN_ + (size_t)b * N_ + s0) * 256 + l;
    float* yp = y + ((size_t)b * N_ + s0) * 128 + (size_t)dir * 64 + l;
    for (int s = 0; s < N_; ++s) {
      float acc[4];
#pragma unroll
      for (int g4 = 0; g4 < 4; ++g4) acc[g4] = bf2f(p[g4 * 64]);
      p += stride;
#pragma unroll
      for (int k4 = 0; k4 < 16; ++k4) {
        float4 hv = *reinterpret_cast<const float4*>(&hs[4 * k4]);
#pragma unroll
        for (int g4 = 0; g4 < 4; ++g4) {
          acc[g4] = fmaf(hv.x, wf[g4*64+4*k4+0], acc[g4]);
          acc[g4] = fmaf(hv.y, wf[g4*64+4*k4+1], acc[g4]);
          acc[g4] = fmaf(hv.z, wf[g4*64+4*k4+2], acc[g4]);
          acc[g4] = fmaf(hv.w, wf[g4*64+4*k4+3], acc[g4]);
        }
      }
      float si_ = __fdividef(1.f, 1.f + __expf(-acc[0]));
      float sf  = __fdividef(1.f, 1.f + __expf(-acc[1]));
      float tg  = 1.f - __fdividef(2.f, __expf(2.f * acc[2]) + 1.f);
      float so  = __fdividef(1.f, 1.f + __expf(-acc[3]));
      c = sf * c + si_ * tg;
      float tc = 1.f - __fdividef(2.f, __expf(2.f * c) + 1.f);
      float hh = so * tc;
      hs[l] = hh;
      *yp = hh;
      yp += ystr;
    }
  }
#endif
}

// ---------------- fallback persistent LSTM (round-3 version, safe path) -------
__global__ __launch_bounds__(256) void k_lstm(
    const float* __restrict__ h2raw, const float* __restrict__ b2,
    const float* __restrict__ WihF, const float* __restrict__ WhhF,
    const float* __restrict__ bihF, const float* __restrict__ bhhF,
    const float* __restrict__ WihB, const float* __restrict__ WhhB,
    const float* __restrict__ bihB, const float* __restrict__ bhhB,
    float* __restrict__ y) {
  const int b   = blockIdx.x & 63;
  const int dir = blockIdx.x >> 6;
  const float* Wih = dir ? WihB : WihF;
  const float* Whh = dir ? WhhB : WhhF;
  const float* bih = dir ? bihB : bihF;
  const float* bhh = dir ? bhhB : bhhF;
  const int j = threadIdx.x;

  float wih[64], whh[64];
#pragma unroll
  for (int k = 0; k < 64; k += 4) {
    *reinterpret_cast<float4*>(&wih[k]) = *reinterpret_cast<const float4*>(&Wih[j * 64 + k]);
    *reinterpret_cast<float4*>(&whh[k]) = *reinterpret_cast<const float4*>(&Whh[j * 64 + k]);
  }
  const float bias = bih[j] + bhh[j];
  const float b2j = (j < 64) ? b2[j] : 0.f;

  __shared__ __align__(16) float xbuf[64];
  __shared__ __align__(16) float hbuf[64];
  __shared__ float gbuf[256];
  float c = 0.f;
  if (j < 64) hbuf[j] = 0.f;

  float xc = 0.f, xn = 0.f;
  if (j < 64) {
    const int s0 = dir ? N_ - 1 : 0;
    const int s1 = dir ? N_ - 2 : 1;
    xc = h2raw[((size_t)b * N_ + s0) * 64 + j];
    xn = h2raw[((size_t)b * N_ + s1) * 64 + j];
  }

  for (int si = 0; si < N_; ++si) {
    const int s = dir ? (N_ - 1 - si) : si;
    const size_t vrow = (size_t)b * N_ + s;
    if (j < 64) xbuf[j] = fmaxf(xc + b2j, 0.f);
    LBAR();

    float xp = 0.f;
    {
      int si2 = si + 2; if (si2 >= N_) si2 = N_ - 1;
      const int s2 = dir ? (N_ - 1 - si2) : si2;
      if (j < 64) xp = h2raw[((size_t)b * N_ + s2) * 64 + j];
    }

    float a0 = 0.f, a1 = 0.f, a2 = 0.f, a3 = 0.f;
#pragma unroll
    for (int k = 0; k < 64; k += 16) {
      float4 xv0 = *reinterpret_cast<const float4*>(&xbuf[k]);
      float4 hv0 = *reinterpret_cast<const float4*>(&hbuf[k]);
      a0 = fmaf(xv0.x, wih[k+0], a0); a0 = fmaf(hv0.x, whh[k+0], a0);
      a0 = fmaf(xv0.y, wih[k+1], a0); a0 = fmaf(hv0.y, whh[k+1], a0);
      a0 = fmaf(xv0.z, wih[k+2], a0); a0 = fmaf(hv0.z, whh[k+2], a0);
      a0 = fmaf(xv0.w, wih[k+3], a0); a0 = fmaf(hv0.w, whh[k+3], a0);
      float4 xv1 = *reinterpret_cast<const float4*>(&xbuf[k+4]);
      float4 hv1 = *reinterpret_cast<const float4*>(&hbuf[k+4]);
      a1 = fmaf(xv1.x, wih[k+4], a1); a1 = fmaf(hv1.x, whh[k+4], a1);
      a1 = fmaf(xv1.y, wih[k+5], a1); a1 = fmaf(hv1.y, whh[k+5], a1);
      a1 = fmaf(xv1.z, wih[k+6], a1); a1 = fmaf(hv1.z, whh[k+6], a1);
      a1 = fmaf(xv1.w, wih[k+7], a1); a1 = fmaf(hv1.w, whh[k+7], a1);
      float4 xv2 = *reinterpret_cast<const float4*>(&xbuf[k+8]);
      float4 hv2 = *reinterpret_cast<const float4*>(&hbuf[k+8]);
      a2 = fmaf(xv2.x, wih[k+8], a2); a2 = fmaf(hv2.x, whh[k+8], a2);
      a2 = fmaf(xv2.y, wih[k+9], a2); a2 = fmaf(hv2.y, whh[k+9], a2);
      a2 = fmaf(xv2.z, wih[k+10], a2); a2 = fmaf(hv2.z, whh[k+10], a2);
      a2 = fmaf(xv2.w, wih[k+11], a2); a2 = fmaf(hv2.w, whh[k+11], a2);
      float4 xv3 = *reinterpret_cast<const float4*>(&xbuf[k+12]);
      float4 hv3 = *reinterpret_cast<const float4*>(&hbuf[k+12]);
      a3 = fmaf(xv3.x, wih[k+12], a3); a3 = fmaf(hv3.x, whh[k+12], a3);
      a3 = fmaf(xv3.y, wih[k+13], a3); a3 = fmaf(hv3.y, whh[k+13], a3);
      a3 = fmaf(xv3.z, wih[k+14], a3); a3 = fmaf(hv3.z, whh[k+14], a3);
      a3 = fmaf(xv3.w, wih[k+15], a3); a3 = fmaf(hv3.w, whh[k+15], a3);
    }
    gbuf[j] = bias + (a0 + a1) + (a2 + a3);
    LBAR();

    if (j < 64) {
      float gi = gbuf[j], gf = gbuf[64 + j], gg = gbuf[128 + j], go = gbuf[192 + j];
      float si_ = __fdividef(1.f, 1.f + __expf(-gi));
      float sf  = __fdividef(1.f, 1.f + __expf(-gf));
      float so  = __fdividef(1.f, 1.f + __expf(-go));
      float tg  = 1.f - __fdividef(2.f, __expf(2.f * gg) + 1.f);
      c = sf * c + si_ * tg;
      float tc = 1.f - __fdividef(2.f, __expf(2.f * c) + 1.f);
      float hh = so * tc;
      hbuf[j] = hh;
      y[vrow * 128 + (size_t)dir * 64 + j] = hh;
    }
    xc = xn; xn = xp;
  }
}

// ---------------- decoder + masked MSE (LDS-staged y rows) ----------------
__global__ __launch_bounds__(256) void k_decoder(
    const float* __restrict__ y, const float* __restrict__ x,
    const float* __restrict__ mask, const float* __restrict__ Wd,
    const float* __restrict__ bd, float* __restrict__ out,
    float* __restrict__ accum) {
  __shared__ float ys[16 * 132];           // 16 rows, padded to 132 floats
  const int tid = threadIdx.x;
  const size_t base = (size_t)blockIdx.x * 2048;
#pragma unroll
  for (int u = 0; u < 2; ++u) {
    int idx = u * 1024 + tid * 4;
    *reinterpret_cast<float4*>(&ys[(idx >> 7) * 132 + (idx & 127)]) =
        *reinterpret_cast<const float4*>(&y[base + idx]);
  }
  __syncthreads();
  size_t v = (size_t)blockIdx.x * 16 + (tid >> 4);
  int f = tid & 15;
  const float* yr = &ys[(tid >> 4) * 132];
  float acc = bd[f];
#pragma unroll
  for (int jj = 0; jj < 128; jj += 4) {
    float4 yv = *reinterpret_cast<const float4*>(&yr[jj]);
    float4 wv = *reinterpret_cast<const float4*>(&Wd[f * 128 + jj]);
    acc = fmaf(yv.x, wv.x, acc); acc = fmaf(yv.y, wv.y, acc);
    acc = fmaf(yv.z, wv.z, acc); acc = fmaf(yv.w, wv.w, acc);
  }
  size_t o = v * 16 + f;
  float xv = x[o], m = mask[o];
  float d = acc - xv;
  out[o] = (m != 0.f) ? xv : acc;
  float num = m * d * d;
  float den = m;
#pragma unroll
  for (int off = 32; off > 0; off >>= 1) {
    num += __shfl_down(num, off);
    den += __shfl_down(den, off);
  }
  if ((tid & 63) == 0) {
    unsafeAtomicAdd(&accum[0], num);
    unsafeAtomicAdd(&accum[1], den);
  }
}

__global__ void k_loss(const float* __restrict__ accum, float* __restrict__ out_loss) {
  if (threadIdx.x == 0) out_loss[0] = accum[0] / (accum[1] + 1e-8f);
}

// ---------------- launch ----------------
extern "C" void kernel_launch(void* const* d_in, const int* in_sizes, int n_in,
                              void* d_out, int out_size, void* d_ws, size_t ws_size,
                              hipStream_t stream) {
  const float* x    = (const float*)d_in[0];
  const int*   ei   = (const int*)d_in[1];   // row = ei, col = ei + E_
  const float* mask = (const float*)d_in[2];
  const float* W1 = (const float*)d_in[3];
  const float* b1 = (const float*)d_in[4];
  const float* W2 = (const float*)d_in[5];
  const float* b2 = (const float*)d_in[6];
  const float* WihF = (const float*)d_in[7];
  const float* WhhF = (const float*)d_in[8];
  const float* bihF = (const float*)d_in[9];
  const float* bhhF = (const float*)d_in[10];
  const float* WihB = (const float*)d_in[11];
  const float* WhhB = (const float*)d_in[12];
  const float* bihB = (const float*)d_in[13];
  const float* bhhB = (const float*)d_in[14];
  const float* Wd = (const float*)d_in[15];
  const float* bd = (const float*)d_in[16];
  float* out = (float*)d_out;

  // layout: dinv | accum | Y(67M) | C(33.5M) | A(33.5M, gx overlays A +134M)
  float* dinv  = (float*)d_ws;
  float* accum = dinv + NN_;
  float* Y     = accum + 64;
  float* C     = Y + (size_t)NN_ * 128;
  float* A     = C + (size_t)NN_ * 64;
  ushort_t* gx = (ushort_t*)A;
  // sort scratch overlays Y (dead until LSTM writes it)
  int*    srow   = (int*)Y;
  uint_t* cnt    = (uint_t*)(srow + E_);
  uint_t* start  = cnt + NN_;
  uint_t* cursor = start + NN_ + 1;
  uint_t* bsum   = cursor + NN_;

  size_t need = ((char*)A - (char*)d_ws) + 2ull * NN_ * 256 * sizeof(ushort_t);
  bool use_gx = ws_size >= need;

  // ---- degree + col-sort ----
  k_zero<<<NN_ / 256, 256, 0, stream>>>(cnt, accum);
  k_hist<<<E_ / 256, 256, 0, stream>>>(ei + E_, cnt);
  k_dinvc<<<NN_ / 256, 256, 0, stream>>>(cnt, dinv);
  k_bsum<<<512, 256, 0, stream>>>(cnt, bsum);
  k_scan512<<<1, 512, 0, stream>>>(bsum);
  k_scanadd<<<512, 256, 0, stream>>>(cnt, bsum, start, cursor);
  k_place<<<E_ / 256, 256, 0, stream>>>(ei, ei + E_, cursor, srow);

  // ---- GCN layer 1 ----
  k_gemm<FIN_, false><<<NN_ / 4, 256, 0, stream>>>(x, W1, nullptr, dinv, A);
  k_colagg<<<NN_ / 4, 256, 0, stream>>>(srow, start, dinv, A, C);

  // ---- GCN layer 2 ----
  k_gemm<64, true><<<NN_ / 4, 256, 0, stream>>>(C, W2, b1, dinv, A);
  k_colagg<<<NN_ / 4, 256, 0, stream>>>(srow, start, dinv, A, C);

  if (use_gx) {
    k_gates<<<2 * (NN_ / 64), 256, 0, stream>>>(C, b2, WihF, bihF, bhhF,
                                                WihB, bihB, bhhB, gx);
    k_lstm4<<<128, 128, 0, stream>>>(gx, WhhF, WhhB, Y);
  } else {
    k_lstm<<<128, 256, 0, stream>>>(C, b2, WihF, WhhF, bihF, bhhF,
                                    WihB, WhhB, bihB, bhhB, Y);
  }

  k_decoder<<<NN_ / 16, 256, 0, stream>>>(Y, x, mask, Wd, bd, out, accum);
  k_loss<<<1, 64, 0, stream>>>(accum, out + (size_t)NN_ * FIN_);
}